// Round 1
// baseline (1222.551 us; speedup 1.0000x reference)
//
#include <hip/hip_runtime.h>
#include <cstdint>
#include <cstddef>

#define Nn    4096
#define Ee    131072
#define INC   512
#define HIDC  512
#define HEADS 4
#define NLAY  3
#define GG    16
#define FW    2048   // HEADS*HIDC

// ---------------- W_gat [h][c][d] -> Wt [c][h*512+d] ----------------
__global__ __launch_bounds__(256) void transpose_wgat(const float* __restrict__ Wg, float* __restrict__ Wt){
  int idx = blockIdx.x*256 + threadIdx.x;           // 4*512*512 total
  int d = idx & 511; int c = (idx>>9) & 511; int h = idx>>18;
  Wt[(size_t)c*FW + h*HIDC + d] = Wg[(size_t)h*INC*HIDC + (size_t)c*HIDC + d];
}

// ---------------- generic fp32 SGEMM, 64x64 tile, 4x4 microtile ----------------
// C[M,N] = A[M,K] @ B[K,N]; if relu_res: C = relu(A@B) + Res
__global__ __launch_bounds__(256) void sgemm(const float* __restrict__ A, const float* __restrict__ B,
    const float* __restrict__ Res, float* __restrict__ C, int M, int N, int K, int relu_res)
{
  __shared__ float As[16][68];
  __shared__ float Bs[16][64];
  int t = threadIdx.x;
  int m0 = blockIdx.y*64, n0 = blockIdx.x*64;
  int arow = t>>2, akq = t&3;
  int bk = t>>4, bnq = t&15;
  const float* Ap = A + (size_t)(m0+arow)*K + akq*4;
  const float* Bp = B + (size_t)bk*N + n0 + bnq*4;
  int tx = t&15, ty = t>>4;
  float acc[4][4];
  #pragma unroll
  for (int i=0;i<4;i++){
    #pragma unroll
    for (int j=0;j<4;j++) acc[i][j]=0.f;
  }
  float4 av = *(const float4*)Ap;
  float4 bv = *(const float4*)Bp;
  for (int k0=0; k0<K; k0+=16){
    As[akq*4+0][arow]=av.x; As[akq*4+1][arow]=av.y; As[akq*4+2][arow]=av.z; As[akq*4+3][arow]=av.w;
    *(float4*)&Bs[bk][bnq*4] = bv;
    __syncthreads();
    if (k0+16 < K){
      av = *(const float4*)(Ap + k0 + 16);
      bv = *(const float4*)(Bp + (size_t)(k0+16)*N);
    }
    #pragma unroll
    for (int k=0;k<16;k++){
      float4 a = *(const float4*)&As[k][ty*4];
      float4 b = *(const float4*)&Bs[k][tx*4];
      acc[0][0]+=a.x*b.x; acc[0][1]+=a.x*b.y; acc[0][2]+=a.x*b.z; acc[0][3]+=a.x*b.w;
      acc[1][0]+=a.y*b.x; acc[1][1]+=a.y*b.y; acc[1][2]+=a.y*b.z; acc[1][3]+=a.y*b.w;
      acc[2][0]+=a.z*b.x; acc[2][1]+=a.z*b.y; acc[2][2]+=a.z*b.z; acc[2][3]+=a.z*b.w;
      acc[3][0]+=a.w*b.x; acc[3][1]+=a.w*b.y; acc[3][2]+=a.w*b.z; acc[3][3]+=a.w*b.w;
    }
    __syncthreads();
  }
  #pragma unroll
  for (int i=0;i<4;i++){
    size_t off = (size_t)(m0+ty*4+i)*N + n0 + tx*4;
    float4 v = make_float4(acc[i][0],acc[i][1],acc[i][2],acc[i][3]);
    if (relu_res){
      const float4 r = *(const float4*)(Res + off);
      v.x = fmaxf(v.x,0.f)+r.x; v.y = fmaxf(v.y,0.f)+r.y;
      v.z = fmaxf(v.z,0.f)+r.z; v.w = fmaxf(v.w,0.f)+r.w;
    }
    *(float4*)(C + off) = v;
  }
}

// ---------------- attention logits per (node,head) ----------------
__global__ __launch_bounds__(256) void compute_lg(const float* __restrict__ h,
    const float* __restrict__ a_src, const float* __restrict__ a_dst,
    float* __restrict__ lgs, float* __restrict__ lgd){
  int n = blockIdx.x; int t = threadIdx.x;
  int hd = t>>6, lane = t&63;
  const float* hp = h + (size_t)n*FW + hd*HIDC;
  const float* as = a_src + hd*HIDC;
  const float* ad = a_dst + hd*HIDC;
  float s1=0.f, s2=0.f;
  for (int d=lane; d<HIDC; d+=64){ float v=hp[d]; s1 += v*as[d]; s2 += v*ad[d]; }
  for (int off=32; off; off>>=1){ s1 += __shfl_down(s1,off); s2 += __shfl_down(s2,off); }
  if (lane==0){ lgs[n*HEADS+hd]=s1; lgd[n*HEADS+hd]=s2; }
}

// ---------------- CSR build helpers ----------------
__global__ __launch_bounds__(256) void hist_dst(const int* __restrict__ dst, int* __restrict__ indeg){
  int e = blockIdx.x*256+threadIdx.x; if (e<Ee) atomicAdd(&indeg[dst[e]],1);
}
__global__ __launch_bounds__(1024) void exscan(const int* __restrict__ cnt, int* __restrict__ rowptr, int n){
  __shared__ int sums[1024];
  int t = threadIdx.x;
  int v[4]; int s=0;
  #pragma unroll
  for (int i=0;i<4;i++){ int idx=t*4+i; v[i] = (idx<n)? cnt[idx] : 0; s+=v[i]; }
  sums[t]=s; __syncthreads();
  for (int off=1; off<1024; off<<=1){
    int other = (t>=off)? sums[t-off] : 0;
    __syncthreads();
    sums[t] += other;
    __syncthreads();
  }
  int run = (t>0)? sums[t-1] : 0;
  #pragma unroll
  for (int i=0;i<4;i++){ int idx=t*4+i; if (idx<n) rowptr[idx]=run; run+=v[i]; }
  if (t==1023) rowptr[n]=sums[1023];
}
__global__ __launch_bounds__(256) void scatter_dst(const int* __restrict__ dst, const int* __restrict__ rowptr,
    int* __restrict__ fill, int* __restrict__ elist){
  int e = blockIdx.x*256+threadIdx.x; if (e>=Ee) return;
  int d = dst[e]; int p = atomicAdd(&fill[d],1); elist[rowptr[d]+p]=e;
}
// dedup for dense-adjacency semantics (.set, not .add)
__global__ __launch_bounds__(256) void dedup_mark(const int* __restrict__ src, const int* __restrict__ dst,
    unsigned int* __restrict__ bitmap, int* __restrict__ cnt, int* __restrict__ flag){
  int e = blockIdx.x*256+threadIdx.x; if (e>=Ee) return;
  unsigned int key = (unsigned int)src[e]*Nn + (unsigned int)dst[e];
  unsigned int bit = 1u<<(key&31);
  unsigned int old = atomicOr(&bitmap[key>>5], bit);
  if (!(old & bit)){ flag[e]=1; atomicAdd(&cnt[src[e]],1); }
}
__global__ __launch_bounds__(256) void scatter_src(const int* __restrict__ src, const int* __restrict__ dst,
    const int* __restrict__ flag, const int* __restrict__ rowptr, int* __restrict__ fill, int* __restrict__ cols){
  int e = blockIdx.x*256+threadIdx.x; if (e>=Ee) return;
  if (!flag[e]) return;
  int s = src[e]; int p = atomicAdd(&fill[s],1); cols[rowptr[s]+p] = dst[e];
}
__global__ __launch_bounds__(256) void compute_dinv(const int* __restrict__ cnt, float* __restrict__ dinv){
  int n = blockIdx.x*256+threadIdx.x; if (n<Nn) dinv[n] = 1.0f/sqrtf((float)(1+cnt[n]));
}

// ---------------- GAT softmax-aggregate per (node, head) ----------------
__global__ __launch_bounds__(256) void gat_aggregate(const float* __restrict__ h,
    const float* __restrict__ lgs, const float* __restrict__ lgd,
    const int* __restrict__ srcArr, const int* __restrict__ rowptr, const int* __restrict__ elist,
    float* __restrict__ Hout){
  __shared__ float red[4];
  __shared__ float al[256];
  __shared__ int ssrc[256];
  int n = blockIdx.x, hd = blockIdx.y;
  int t = threadIdx.x;
  int beg = rowptr[n], deg = rowptr[n+1]-beg;
  float ldst = lgd[n*HEADS+hd];
  // pass 1: max
  float mx = -3.4e38f;
  for (int i=t; i<deg; i+=256){
    int e = elist[beg+i]; float v = lgs[srcArr[e]*HEADS+hd] + ldst;
    v = v>0.f ? v : 0.2f*v; mx = fmaxf(mx,v);
  }
  for (int off=32; off; off>>=1) mx = fmaxf(mx, __shfl_down(mx,off));
  if ((t&63)==0) red[t>>6]=mx;
  __syncthreads();
  mx = fmaxf(fmaxf(red[0],red[1]), fmaxf(red[2],red[3]));
  // pass 2: denominator
  float zs = 0.f;
  for (int i=t; i<deg; i+=256){
    int e = elist[beg+i]; float v = lgs[srcArr[e]*HEADS+hd] + ldst;
    v = v>0.f ? v : 0.2f*v; zs += expf(v-mx);
  }
  for (int off=32; off; off>>=1) zs += __shfl_down(zs,off);
  __syncthreads();
  if ((t&63)==0) red[t>>6]=zs;
  __syncthreads();
  zs = red[0]+red[1]+red[2]+red[3];
  float inv = 1.f/(zs+1e-16f);
  // pass 3: weighted accumulate (chunks of 256 edges)
  float2 acc = make_float2(0.f,0.f);
  for (int base=0; base<deg; base+=256){
    int i = base+t;
    if (i<deg){
      int e = elist[beg+i]; int s = srcArr[e];
      float v = lgs[s*HEADS+hd] + ldst; v = v>0.f ? v : 0.2f*v;
      al[t] = expf(v-mx)*inv; ssrc[t] = s;
    }
    __syncthreads();
    int cn = min(256, deg-base);
    for (int c=0;c<cn;c++){
      float a = al[c];
      float2 hv = *(const float2*)(h + (size_t)ssrc[c]*FW + hd*HIDC + t*2);
      acc.x += a*hv.x; acc.y += a*hv.y;
    }
    __syncthreads();
  }
  *(float2*)(Hout + (size_t)n*FW + hd*HIDC + t*2) = acc;
}

// ---------------- SpMM: P = A_hat @ H (sparse rows + explicit diagonal) ----------------
__global__ __launch_bounds__(256) void spmm_ahat(const float* __restrict__ Hin, float* __restrict__ P,
    const int* __restrict__ rowptr, const int* __restrict__ cols, const float* __restrict__ dinv){
  int n = blockIdx.x; int t = threadIdx.x;
  float di = dinv[n];
  const float4* Hn = (const float4*)(Hin + (size_t)n*FW);
  float w0 = di*di;
  float4 x = Hn[t], y = Hn[t+256];
  float4 acc0 = make_float4(w0*x.x, w0*x.y, w0*x.z, w0*x.w);
  float4 acc1 = make_float4(w0*y.x, w0*y.y, w0*y.z, w0*y.w);
  int beg = rowptr[n], end = rowptr[n+1];
  for (int i=beg;i<end;i++){
    int m = cols[i]; float w = di*dinv[m];
    const float4* Hm = (const float4*)(Hin + (size_t)m*FW);
    float4 u = Hm[t], v = Hm[t+256];
    acc0.x += w*u.x; acc0.y += w*u.y; acc0.z += w*u.z; acc0.w += w*u.w;
    acc1.x += w*v.x; acc1.y += w*v.y; acc1.z += w*v.z; acc1.w += w*v.w;
  }
  ((float4*)(P + (size_t)n*FW))[t]     = acc0;
  ((float4*)(P + (size_t)n*FW))[t+256] = acc1;
}

// ---------------- pooling ----------------
__global__ __launch_bounds__(256) void graph_offsets(const int* __restrict__ batch, int* __restrict__ goff){
  __shared__ int cnt[GG];
  int t = threadIdx.x;
  if (t<GG) cnt[t]=0;
  __syncthreads();
  for (int i=t;i<Nn;i+=256) atomicAdd(&cnt[batch[i]],1);
  __syncthreads();
  if (t==0){ int run=0; for (int g=0; g<GG; g++){ goff[g]=run; run+=cnt[g]; } goff[GG]=run; }
}
__global__ __launch_bounds__(256) void pool_mean(const float* __restrict__ H, const int* __restrict__ goff,
    float* __restrict__ pooled){
  int g = blockIdx.x; int d = blockIdx.y*256 + threadIdx.x;
  int beg=goff[g], end=goff[g+1];
  float s=0.f;
  for (int n=beg;n<end;n++) s += H[(size_t)n*FW + d];
  pooled[(size_t)g*FW + d] = s / fmaxf((float)(end-beg), 1.f);
}
__global__ __launch_bounds__(256) void final_out(const float* __restrict__ pooled,
    const float* __restrict__ fc_w, const float* __restrict__ fc_b, float* __restrict__ out){
  int g = blockIdx.x; int t = threadIdx.x;
  float p = 0.f;
  for (int d=t; d<HIDC; d+=256){
    float f = 0.25f*(pooled[(size_t)g*FW+d] + pooled[(size_t)g*FW+HIDC+d]
                   + pooled[(size_t)g*FW+2*HIDC+d] + pooled[(size_t)g*FW+3*HIDC+d]);
    p += f*fc_w[d];
  }
  __shared__ float red[4];
  for (int off=32; off; off>>=1) p += __shfl_down(p,off);
  if ((t&63)==0) red[t>>6]=p;
  __syncthreads();
  if (t==0) out[g] = red[0]+red[1]+red[2]+red[3] + fc_b[0];
}

extern "C" void kernel_launch(void* const* d_in, const int* in_sizes, int n_in,
                              void* d_out, int out_size, void* d_ws, size_t ws_size,
                              hipStream_t stream){
  const float* x      = (const float*)d_in[0];
  const int*   ei     = (const int*)d_in[1];
  const int*   batch  = (const int*)d_in[2];
  const float* W_gat  = (const float*)d_in[3];
  const float* a_src  = (const float*)d_in[4];
  const float* a_dst  = (const float*)d_in[5];
  const float* W_gcn  = (const float*)d_in[6];
  const float* fc_w   = (const float*)d_in[7];
  const float* fc_b   = (const float*)d_in[8];
  float* out = (float*)d_out;
  const int* src = ei;
  const int* dst = ei + Ee;

  char* w = (char*)d_ws;
  size_t off = 0;
  auto alloc = [&](size_t bytes)->char*{ char* p = w + off; off = (off + bytes + 255) & ~(size_t)255; return p; };
  float* hbuf   = (float*)alloc((size_t)Nn*FW*4);   // h after GAT proj; reused as P in GCN layers
  float* Hfeat  = (float*)alloc((size_t)Nn*FW*4);   // node features H
  float* Wt     = (float*)alloc((size_t)INC*FW*4);
  float* lgs    = (float*)alloc((size_t)Nn*HEADS*4);
  float* lgd    = (float*)alloc((size_t)Nn*HEADS*4);
  int* indeg    = (int*)alloc(Nn*4);
  int* rowptr_d = (int*)alloc((Nn+1)*4);
  int* elist    = (int*)alloc(Ee*4);
  int* fill_d   = (int*)alloc(Nn*4);
  unsigned int* bitmap = (unsigned int*)alloc((size_t)Nn*Nn/8);
  int* cnt_s    = (int*)alloc(Nn*4);
  int* rowptr_s = (int*)alloc((Nn+1)*4);
  int* cols     = (int*)alloc(Ee*4);
  int* fill_s   = (int*)alloc(Nn*4);
  int* flag     = (int*)alloc(Ee*4);
  float* dinv   = (float*)alloc(Nn*4);
  float* pooled = (float*)alloc((size_t)GG*FW*4);
  int* goff     = (int*)alloc((GG+1)*4);

  hipMemsetAsync(indeg, 0, Nn*4, stream);
  hipMemsetAsync(fill_d, 0, Nn*4, stream);
  hipMemsetAsync(cnt_s, 0, Nn*4, stream);
  hipMemsetAsync(fill_s, 0, Nn*4, stream);
  hipMemsetAsync(flag, 0, Ee*4, stream);
  hipMemsetAsync(bitmap, 0, (size_t)Nn*Nn/8, stream);

  // ---- GAT ----
  transpose_wgat<<<4096,256,0,stream>>>(W_gat, Wt);
  sgemm<<<dim3(FW/64, Nn/64), 256, 0, stream>>>(x, Wt, nullptr, hbuf, Nn, FW, INC, 0);
  compute_lg<<<Nn,256,0,stream>>>(hbuf, a_src, a_dst, lgs, lgd);
  hist_dst<<<Ee/256,256,0,stream>>>(dst, indeg);
  exscan<<<1,1024,0,stream>>>(indeg, rowptr_d, Nn);
  scatter_dst<<<Ee/256,256,0,stream>>>(dst, rowptr_d, fill_d, elist);
  gat_aggregate<<<dim3(Nn,HEADS),256,0,stream>>>(hbuf, lgs, lgd, src, rowptr_d, elist, Hfeat);

  // ---- dedup'd adjacency (set-semantics) + GCN normalization ----
  dedup_mark<<<Ee/256,256,0,stream>>>(src, dst, bitmap, cnt_s, flag);
  exscan<<<1,1024,0,stream>>>(cnt_s, rowptr_s, Nn);
  scatter_src<<<Ee/256,256,0,stream>>>(src, dst, flag, rowptr_s, fill_s, cols);
  compute_dinv<<<Nn/256,256,0,stream>>>(cnt_s, dinv);

  // ---- residual GCN layers ----
  for (int l=0;l<NLAY;l++){
    spmm_ahat<<<Nn,256,0,stream>>>(Hfeat, hbuf, rowptr_s, cols, dinv);
    sgemm<<<dim3(HIDC/64, (Nn*HEADS)/64), 256, 0, stream>>>(hbuf, W_gcn + (size_t)l*HIDC*HIDC,
                                                            Hfeat, Hfeat, Nn*HEADS, HIDC, HIDC, 1);
  }

  // ---- pooling + FC ----
  graph_offsets<<<1,256,0,stream>>>(batch, goff);
  pool_mean<<<dim3(GG, FW/256),256,0,stream>>>(Hfeat, goff, pooled);
  final_out<<<GG,256,0,stream>>>(pooled, fc_w, fc_b, out);
}

// Round 2
// 696.162 us; speedup vs baseline: 1.7561x; 1.7561x over previous
//
#include <hip/hip_runtime.h>
#include <cstdint>
#include <cstddef>

#define Nn    4096
#define Ee    131072
#define INC   512
#define HIDC  512
#define HEADS 4
#define NLAY  3
#define GG    16
#define FW    2048   // HEADS*HIDC
#define LDA   40     // padded LDS row stride (shorts) for 32-k tiles

typedef __attribute__((ext_vector_type(8))) short bfrag;   // 8 bf16 (4 VGPRs)
typedef __attribute__((ext_vector_type(4))) float ffrag;   // 4 fp32 acc

__device__ __forceinline__ ushort f2bf(float v){
  uint u = __builtin_bit_cast(uint, v);
  u += 0x7fffu + ((u>>16)&1u);          // RNE
  return (ushort)(u>>16);
}
__device__ __forceinline__ float bf2f(ushort s){
  uint u = ((uint)s)<<16; return __builtin_bit_cast(float, u);
}

// ---------------- split fp32 -> (hi,lo) bf16, elementwise ----------------
__global__ __launch_bounds__(256) void split_f32(const float* __restrict__ X,
    ushort* __restrict__ Xhi, ushort* __restrict__ Xlo){
  int i = blockIdx.x*256 + threadIdx.x;
  float v = X[i];
  ushort h = f2bf(v);
  Xhi[i] = h; Xlo[i] = f2bf(v - bf2f(h));
}

// ---------------- batched 512x512 transpose + hi/lo split ----------------
// in: W[b][r][c]  ->  out block b (offset b*512*512): T[c][r]
__global__ __launch_bounds__(256) void tsplit(const float* __restrict__ W,
    ushort* __restrict__ Thi, ushort* __restrict__ Tlo){
  __shared__ float tile[32][33];
  int b = blockIdx.z;
  int r0 = blockIdx.y*32, c0 = blockIdx.x*32;
  int t = threadIdx.x;
  int i = t>>3, j0 = (t&7)*4;
  const float* Wb = W + (size_t)b*512*512;
  float4 v = *(const float4*)(Wb + (size_t)(r0+i)*512 + c0 + j0);
  tile[i][j0]=v.x; tile[i][j0+1]=v.y; tile[i][j0+2]=v.z; tile[i][j0+3]=v.w;
  __syncthreads();
  ushort* oh = Thi + (size_t)b*512*512 + (size_t)(c0+i)*512 + r0 + j0;
  ushort* ol = Tlo + (size_t)b*512*512 + (size_t)(c0+i)*512 + r0 + j0;
  #pragma unroll
  for (int q=0;q<4;q++){
    float f = tile[j0+q][i];
    ushort h = f2bf(f);
    oh[q]=h; ol[q]=f2bf(f - bf2f(h));
  }
}

// ---------------- bf16x3 MFMA GEMM: C = (Ahi+Alo)(Bhi+Blo), 128x128 tile ----------------
// A row-major [M][K] hi/lo; B TRANSPOSED [N][K] hi/lo.
// relu_res: C = relu(AB)+Res. Cf (fp32) and Cb (bf16) optional outputs.
__global__ __launch_bounds__(256) void gemm_x3(
    const ushort* __restrict__ Ahi, const ushort* __restrict__ Alo,
    const ushort* __restrict__ Bhi, const ushort* __restrict__ Blo,
    const float* __restrict__ Res, float* __restrict__ Cf, ushort* __restrict__ Cb,
    int M, int N, int K, int relu_res)
{
  __shared__ __align__(16) ushort Ah[128*LDA];
  __shared__ __align__(16) ushort Al[128*LDA];
  __shared__ __align__(16) ushort Bh[128*LDA];
  __shared__ __align__(16) ushort Bl[128*LDA];
  int t = threadIdx.x;
  int m0 = blockIdx.y*128, n0 = blockIdx.x*128;
  int srow = t>>1, scol = (t&1)*16;              // stage: 2 threads/row, 16 shorts each
  int wave = t>>6, lane = t&63;
  int wm = (wave&1)*64, wn = (wave>>1)*64;
  int lm = lane&15, quad = lane>>4;

  ffrag acc[4][4];
  #pragma unroll
  for (int i=0;i<4;i++){
    #pragma unroll
    for (int j=0;j<4;j++) acc[i][j] = (ffrag){0.f,0.f,0.f,0.f};
  }

  const ushort* pAh = Ahi + (size_t)(m0+srow)*K + scol;
  const ushort* pAl = Alo + (size_t)(m0+srow)*K + scol;
  const ushort* pBh = Bhi + (size_t)(n0+srow)*K + scol;
  const ushort* pBl = Blo + (size_t)(n0+srow)*K + scol;

  uint4 ra0 = *(const uint4*)(pAh);     uint4 ra1 = *(const uint4*)(pAh+8);
  uint4 rl0 = *(const uint4*)(pAl);     uint4 rl1 = *(const uint4*)(pAl+8);
  uint4 rb0 = *(const uint4*)(pBh);     uint4 rb1 = *(const uint4*)(pBh+8);
  uint4 rm0 = *(const uint4*)(pBl);     uint4 rm1 = *(const uint4*)(pBl+8);

  int sidx = srow*LDA + scol;
  for (int k0 = 0; k0 < K; k0 += 32){
    __syncthreads();
    *(uint4*)&Ah[sidx] = ra0; *(uint4*)&Ah[sidx+8] = ra1;
    *(uint4*)&Al[sidx] = rl0; *(uint4*)&Al[sidx+8] = rl1;
    *(uint4*)&Bh[sidx] = rb0; *(uint4*)&Bh[sidx+8] = rb1;
    *(uint4*)&Bl[sidx] = rm0; *(uint4*)&Bl[sidx+8] = rm1;
    __syncthreads();
    if (k0+32 < K){
      ra0 = *(const uint4*)(pAh+k0+32); ra1 = *(const uint4*)(pAh+k0+40);
      rl0 = *(const uint4*)(pAl+k0+32); rl1 = *(const uint4*)(pAl+k0+40);
      rb0 = *(const uint4*)(pBh+k0+32); rb1 = *(const uint4*)(pBh+k0+40);
      rm0 = *(const uint4*)(pBl+k0+32); rm1 = *(const uint4*)(pBl+k0+40);
    }
    bfrag af_h[4], af_l[4];
    #pragma unroll
    for (int mt=0; mt<4; mt++){
      af_h[mt] = *(const bfrag*)&Ah[(wm+mt*16+lm)*LDA + quad*8];
      af_l[mt] = *(const bfrag*)&Al[(wm+mt*16+lm)*LDA + quad*8];
    }
    #pragma unroll
    for (int nt=0; nt<4; nt++){
      bfrag bh = *(const bfrag*)&Bh[(wn+nt*16+lm)*LDA + quad*8];
      bfrag bl = *(const bfrag*)&Bl[(wn+nt*16+lm)*LDA + quad*8];
      #pragma unroll
      for (int mt=0; mt<4; mt++){
        acc[mt][nt] = __builtin_amdgcn_mfma_f32_16x16x32_bf16(af_h[mt], bh, acc[mt][nt], 0,0,0);
        acc[mt][nt] = __builtin_amdgcn_mfma_f32_16x16x32_bf16(af_h[mt], bl, acc[mt][nt], 0,0,0);
        acc[mt][nt] = __builtin_amdgcn_mfma_f32_16x16x32_bf16(af_l[mt], bh, acc[mt][nt], 0,0,0);
      }
    }
  }

  #pragma unroll
  for (int mt=0; mt<4; mt++){
    #pragma unroll
    for (int nt=0; nt<4; nt++){
      #pragma unroll
      for (int r=0;r<4;r++){
        int grow = m0 + wm + mt*16 + quad*4 + r;
        int gcol = n0 + wn + nt*16 + lm;
        size_t off = (size_t)grow*N + gcol;
        float v = acc[mt][nt][r];
        if (relu_res) v = fmaxf(v,0.f) + Res[off];
        if (Cf) Cf[off] = v;
        if (Cb) Cb[off] = f2bf(v);
      }
    }
  }
}

// ---------------- attention logits per (node,head), bf16 h ----------------
__global__ __launch_bounds__(256) void compute_lg(const ushort* __restrict__ hbf,
    const float* __restrict__ a_src, const float* __restrict__ a_dst,
    float* __restrict__ lgs, float* __restrict__ lgd){
  int n = blockIdx.x; int t = threadIdx.x;
  int hd = t>>6, lane = t&63;
  const ushort* hp = hbf + (size_t)n*FW + hd*HIDC;
  const float* as = a_src + hd*HIDC;
  const float* ad = a_dst + hd*HIDC;
  float s1=0.f, s2=0.f;
  for (int d=lane; d<HIDC; d+=64){ float v=bf2f(hp[d]); s1 += v*as[d]; s2 += v*ad[d]; }
  for (int off=32; off; off>>=1){ s1 += __shfl_down(s1,off); s2 += __shfl_down(s2,off); }
  if (lane==0){ lgs[n*HEADS+hd]=s1; lgd[n*HEADS+hd]=s2; }
}

// ---------------- CSR build helpers (unchanged from round 1) ----------------
__global__ __launch_bounds__(256) void hist_dst(const int* __restrict__ dst, int* __restrict__ indeg){
  int e = blockIdx.x*256+threadIdx.x; if (e<Ee) atomicAdd(&indeg[dst[e]],1);
}
__global__ __launch_bounds__(1024) void exscan(const int* __restrict__ cnt, int* __restrict__ rowptr, int n){
  __shared__ int sums[1024];
  int t = threadIdx.x;
  int v[4]; int s=0;
  #pragma unroll
  for (int i=0;i<4;i++){ int idx=t*4+i; v[i] = (idx<n)? cnt[idx] : 0; s+=v[i]; }
  sums[t]=s; __syncthreads();
  for (int off=1; off<1024; off<<=1){
    int other = (t>=off)? sums[t-off] : 0;
    __syncthreads();
    sums[t] += other;
    __syncthreads();
  }
  int run = (t>0)? sums[t-1] : 0;
  #pragma unroll
  for (int i=0;i<4;i++){ int idx=t*4+i; if (idx<n) rowptr[idx]=run; run+=v[i]; }
  if (t==1023) rowptr[n]=sums[1023];
}
__global__ __launch_bounds__(256) void scatter_dst(const int* __restrict__ dst, const int* __restrict__ rowptr,
    int* __restrict__ fill, int* __restrict__ elist){
  int e = blockIdx.x*256+threadIdx.x; if (e>=Ee) return;
  int d = dst[e]; int p = atomicAdd(&fill[d],1); elist[rowptr[d]+p]=e;
}
__global__ __launch_bounds__(256) void dedup_mark(const int* __restrict__ src, const int* __restrict__ dst,
    unsigned int* __restrict__ bitmap, int* __restrict__ cnt, int* __restrict__ flag){
  int e = blockIdx.x*256+threadIdx.x; if (e>=Ee) return;
  unsigned int key = (unsigned int)src[e]*Nn + (unsigned int)dst[e];
  unsigned int bit = 1u<<(key&31);
  unsigned int old = atomicOr(&bitmap[key>>5], bit);
  if (!(old & bit)){ flag[e]=1; atomicAdd(&cnt[src[e]],1); }
}
__global__ __launch_bounds__(256) void scatter_src(const int* __restrict__ src, const int* __restrict__ dst,
    const int* __restrict__ flag, const int* __restrict__ rowptr, int* __restrict__ fill, int* __restrict__ cols){
  int e = blockIdx.x*256+threadIdx.x; if (e>=Ee) return;
  if (!flag[e]) return;
  int s = src[e]; int p = atomicAdd(&fill[s],1); cols[rowptr[s]+p] = dst[e];
}
__global__ __launch_bounds__(256) void compute_dinv(const int* __restrict__ cnt, float* __restrict__ dinv){
  int n = blockIdx.x*256+threadIdx.x; if (n<Nn) dinv[n] = 1.0f/sqrtf((float)(1+cnt[n]));
}

// ---------------- GAT softmax-aggregate per (node, head), bf16 gather ----------------
// writes Hfeat fp32 and Hbf bf16
__global__ __launch_bounds__(256) void gat_aggregate(const ushort* __restrict__ hbf,
    const float* __restrict__ lgs, const float* __restrict__ lgd,
    const int* __restrict__ srcArr, const int* __restrict__ rowptr, const int* __restrict__ elist,
    float* __restrict__ Hfeat, ushort* __restrict__ Hbf){
  __shared__ float red[4];
  __shared__ float al[256];
  __shared__ int ssrc[256];
  int n = blockIdx.x, hd = blockIdx.y;
  int t = threadIdx.x;
  int beg = rowptr[n], deg = rowptr[n+1]-beg;
  float ldst = lgd[n*HEADS+hd];
  float mx = -3.4e38f;
  for (int i=t; i<deg; i+=256){
    int e = elist[beg+i]; float v = lgs[srcArr[e]*HEADS+hd] + ldst;
    v = v>0.f ? v : 0.2f*v; mx = fmaxf(mx,v);
  }
  for (int off=32; off; off>>=1) mx = fmaxf(mx, __shfl_down(mx,off));
  if ((t&63)==0) red[t>>6]=mx;
  __syncthreads();
  mx = fmaxf(fmaxf(red[0],red[1]), fmaxf(red[2],red[3]));
  float zs = 0.f;
  for (int i=t; i<deg; i+=256){
    int e = elist[beg+i]; float v = lgs[srcArr[e]*HEADS+hd] + ldst;
    v = v>0.f ? v : 0.2f*v; zs += expf(v-mx);
  }
  for (int off=32; off; off>>=1) zs += __shfl_down(zs,off);
  __syncthreads();
  if ((t&63)==0) red[t>>6]=zs;
  __syncthreads();
  zs = red[0]+red[1]+red[2]+red[3];
  float inv = 1.f/(zs+1e-16f);
  float2 acc = make_float2(0.f,0.f);
  for (int base=0; base<deg; base+=256){
    int i = base+t;
    if (i<deg){
      int e = elist[beg+i]; int s = srcArr[e];
      float v = lgs[s*HEADS+hd] + ldst; v = v>0.f ? v : 0.2f*v;
      al[t] = expf(v-mx)*inv; ssrc[t] = s;
    }
    __syncthreads();
    int cn = min(256, deg-base);
    for (int c=0;c<cn;c++){
      float a = al[c];
      uint hv = *(const uint*)(hbf + (size_t)ssrc[c]*FW + hd*HIDC + t*2);
      acc.x += a*bf2f((ushort)(hv&0xffff));
      acc.y += a*bf2f((ushort)(hv>>16));
    }
    __syncthreads();
  }
  size_t off = (size_t)n*FW + hd*HIDC + t*2;
  *(float2*)(Hfeat + off) = acc;
  uint packed = (uint)f2bf(acc.x) | ((uint)f2bf(acc.y)<<16);
  *(uint*)(Hbf + off) = packed;
}

// ---------------- SpMM: P = A_hat @ H, bf16 gather, 512-feature chunks ----------------
// writes P split as hi/lo bf16 (GEMM A-operand precision)
__global__ __launch_bounds__(256) void spmm_bf(const ushort* __restrict__ Hbf,
    ushort* __restrict__ Phi, ushort* __restrict__ Plo,
    const int* __restrict__ rowptr, const int* __restrict__ cols, const float* __restrict__ dinv){
  int n = blockIdx.x; int t = threadIdx.x;
  int f = (blockIdx.y<<9) + t*2;
  float di = dinv[n];
  uint hv = *(const uint*)(Hbf + (size_t)n*FW + f);
  float w0 = di*di;
  float a0 = w0*bf2f((ushort)(hv&0xffff));
  float a1 = w0*bf2f((ushort)(hv>>16));
  int i = rowptr[n], end = rowptr[n+1];
  for (; i+1<end; i+=2){
    int mA = cols[i], mB = cols[i+1];
    float wA = di*dinv[mA], wB = di*dinv[mB];
    uint hA = *(const uint*)(Hbf + (size_t)mA*FW + f);
    uint hB = *(const uint*)(Hbf + (size_t)mB*FW + f);
    a0 += wA*bf2f((ushort)(hA&0xffff)) + wB*bf2f((ushort)(hB&0xffff));
    a1 += wA*bf2f((ushort)(hA>>16))    + wB*bf2f((ushort)(hB>>16));
  }
  if (i<end){
    int mA = cols[i]; float wA = di*dinv[mA];
    uint hA = *(const uint*)(Hbf + (size_t)mA*FW + f);
    a0 += wA*bf2f((ushort)(hA&0xffff));
    a1 += wA*bf2f((ushort)(hA>>16));
  }
  ushort h0 = f2bf(a0); ushort l0 = f2bf(a0 - bf2f(h0));
  ushort h1 = f2bf(a1); ushort l1 = f2bf(a1 - bf2f(h1));
  size_t off = (size_t)n*FW + f;
  *(uint*)(Phi + off) = (uint)h0 | ((uint)h1<<16);
  *(uint*)(Plo + off) = (uint)l0 | ((uint)l1<<16);
}

// ---------------- pooling ----------------
__global__ __launch_bounds__(256) void graph_offsets(const int* __restrict__ batch, int* __restrict__ goff){
  __shared__ int cnt[GG];
  int t = threadIdx.x;
  if (t<GG) cnt[t]=0;
  __syncthreads();
  for (int i=t;i<Nn;i+=256) atomicAdd(&cnt[batch[i]],1);
  __syncthreads();
  if (t==0){ int run=0; for (int g=0; g<GG; g++){ goff[g]=run; run+=cnt[g]; } goff[GG]=run; }
}
__global__ __launch_bounds__(256) void pool_mean(const float* __restrict__ H, const int* __restrict__ goff,
    float* __restrict__ pooled){
  int g = blockIdx.x; int d = blockIdx.y*256 + threadIdx.x;
  int beg=goff[g], end=goff[g+1];
  float s=0.f;
  for (int n=beg;n<end;n++) s += H[(size_t)n*FW + d];
  pooled[(size_t)g*FW + d] = s / fmaxf((float)(end-beg), 1.f);
}
__global__ __launch_bounds__(256) void final_out(const float* __restrict__ pooled,
    const float* __restrict__ fc_w, const float* __restrict__ fc_b, float* __restrict__ out){
  int g = blockIdx.x; int t = threadIdx.x;
  float p = 0.f;
  for (int d=t; d<HIDC; d+=256){
    float f = 0.25f*(pooled[(size_t)g*FW+d] + pooled[(size_t)g*FW+HIDC+d]
                   + pooled[(size_t)g*FW+2*HIDC+d] + pooled[(size_t)g*FW+3*HIDC+d]);
    p += f*fc_w[d];
  }
  __shared__ float red[4];
  for (int off=32; off; off>>=1) p += __shfl_down(p,off);
  if ((t&63)==0) red[t>>6]=p;
  __syncthreads();
  if (t==0) out[g] = red[0]+red[1]+red[2]+red[3] + fc_b[0];
}

extern "C" void kernel_launch(void* const* d_in, const int* in_sizes, int n_in,
                              void* d_out, int out_size, void* d_ws, size_t ws_size,
                              hipStream_t stream){
  const float* x      = (const float*)d_in[0];
  const int*   ei     = (const int*)d_in[1];
  const int*   batch  = (const int*)d_in[2];
  const float* W_gat  = (const float*)d_in[3];
  const float* a_src  = (const float*)d_in[4];
  const float* a_dst  = (const float*)d_in[5];
  const float* W_gcn  = (const float*)d_in[6];
  const float* fc_w   = (const float*)d_in[7];
  const float* fc_b   = (const float*)d_in[8];
  float* out = (float*)d_out;
  const int* src = ei;
  const int* dst = ei + Ee;

  char* w = (char*)d_ws;
  size_t off = 0;
  auto alloc = [&](size_t bytes)->char*{ char* p = w + off; off = (off + bytes + 255) & ~(size_t)255; return p; };
  float*  Hfeat  = (float*)alloc((size_t)Nn*FW*4);        // fp32 node features (residual path)
  ushort* hbf    = (ushort*)alloc((size_t)Nn*FW*2);       // bf16 GAT projection; REUSED as Phi in GCN loop
  ushort* Hbf    = (ushort*)alloc((size_t)Nn*FW*2);       // bf16 copy of H for gathers
  ushort* Plo    = (ushort*)alloc((size_t)Nn*FW*2);
  ushort* Xhi    = (ushort*)alloc((size_t)Nn*INC*2);
  ushort* Xlo    = (ushort*)alloc((size_t)Nn*INC*2);
  ushort* WgatThi= (ushort*)alloc((size_t)HEADS*INC*HIDC*2);
  ushort* WgatTlo= (ushort*)alloc((size_t)HEADS*INC*HIDC*2);
  ushort* WgcnThi= (ushort*)alloc((size_t)NLAY*HIDC*HIDC*2);
  ushort* WgcnTlo= (ushort*)alloc((size_t)NLAY*HIDC*HIDC*2);
  float* lgs    = (float*)alloc((size_t)Nn*HEADS*4);
  float* lgd    = (float*)alloc((size_t)Nn*HEADS*4);
  int* indeg    = (int*)alloc(Nn*4);
  int* rowptr_d = (int*)alloc((Nn+1)*4);
  int* elist    = (int*)alloc(Ee*4);
  int* fill_d   = (int*)alloc(Nn*4);
  unsigned int* bitmap = (unsigned int*)alloc((size_t)Nn*Nn/8);
  int* cnt_s    = (int*)alloc(Nn*4);
  int* rowptr_s = (int*)alloc((Nn+1)*4);
  int* cols     = (int*)alloc(Ee*4);
  int* fill_s   = (int*)alloc(Nn*4);
  int* flag     = (int*)alloc(Ee*4);
  float* dinv   = (float*)alloc(Nn*4);
  float* pooled = (float*)alloc((size_t)GG*FW*4);
  int* goff     = (int*)alloc((GG+1)*4);
  ushort* Phi   = hbf;   // projection no longer needed once GCN loop starts

  hipMemsetAsync(indeg, 0, Nn*4, stream);
  hipMemsetAsync(fill_d, 0, Nn*4, stream);
  hipMemsetAsync(cnt_s, 0, Nn*4, stream);
  hipMemsetAsync(fill_s, 0, Nn*4, stream);
  hipMemsetAsync(flag, 0, Ee*4, stream);
  hipMemsetAsync(bitmap, 0, (size_t)Nn*Nn/8, stream);

  // ---- input prep: splits + transposes ----
  split_f32<<<(Nn*INC)/256,256,0,stream>>>(x, Xhi, Xlo);
  tsplit<<<dim3(16,16,HEADS),256,0,stream>>>(W_gat, WgatThi, WgatTlo);
  tsplit<<<dim3(16,16,NLAY),256,0,stream>>>(W_gcn, WgcnThi, WgcnTlo);

  // ---- GAT projection: hbf = bf16(x @ Wt), MFMA bf16x3 ----
  gemm_x3<<<dim3(FW/128, Nn/128),256,0,stream>>>(Xhi, Xlo, WgatThi, WgatTlo,
      nullptr, nullptr, hbf, Nn, FW, INC, 0);
  compute_lg<<<Nn,256,0,stream>>>(hbf, a_src, a_dst, lgs, lgd);

  // ---- CSR by dst for attention ----
  hist_dst<<<Ee/256,256,0,stream>>>(dst, indeg);
  exscan<<<1,1024,0,stream>>>(indeg, rowptr_d, Nn);
  scatter_dst<<<Ee/256,256,0,stream>>>(dst, rowptr_d, fill_d, elist);
  gat_aggregate<<<dim3(Nn,HEADS),256,0,stream>>>(hbf, lgs, lgd, src, rowptr_d, elist, Hfeat, Hbf);

  // ---- dedup'd adjacency (set-semantics) + GCN normalization ----
  dedup_mark<<<Ee/256,256,0,stream>>>(src, dst, bitmap, cnt_s, flag);
  exscan<<<1,1024,0,stream>>>(cnt_s, rowptr_s, Nn);
  scatter_src<<<Ee/256,256,0,stream>>>(src, dst, flag, rowptr_s, fill_s, cols);
  compute_dinv<<<Nn/256,256,0,stream>>>(cnt_s, dinv);

  // ---- residual GCN layers ----
  for (int l=0;l<NLAY;l++){
    spmm_bf<<<dim3(Nn,4),256,0,stream>>>(Hbf, Phi, Plo, rowptr_s, cols, dinv);
    gemm_x3<<<dim3(HIDC/128, (Nn*HEADS)/128),256,0,stream>>>(Phi, Plo,
        WgcnThi + (size_t)l*HIDC*HIDC, WgcnTlo + (size_t)l*HIDC*HIDC,
        Hfeat, Hfeat, Hbf, Nn*HEADS, HIDC, HIDC, 1);
  }

  // ---- pooling + FC ----
  graph_offsets<<<1,256,0,stream>>>(batch, goff);
  pool_mean<<<dim3(GG, FW/256),256,0,stream>>>(Hfeat, goff, pooled);
  final_out<<<GG,256,0,stream>>>(pooled, fc_w, fc_b, out);
}

// Round 3
// 590.411 us; speedup vs baseline: 2.0707x; 1.1791x over previous
//
#include <hip/hip_runtime.h>
#include <cstdint>
#include <cstddef>

#define Nn    4096
#define Ee    131072
#define INC   512
#define HIDC  512
#define HEADS 4
#define NLAY  3
#define GG    16
#define FW    2048   // HEADS*HIDC
#define LDA   40     // padded LDS row stride (shorts) for 32-k tiles

typedef __attribute__((ext_vector_type(8))) short bfrag;   // 8 bf16 (4 VGPRs)
typedef __attribute__((ext_vector_type(4))) float ffrag;   // 4 fp32 acc

__device__ __forceinline__ ushort f2bf(float v){
  uint u = __builtin_bit_cast(uint, v);
  u += 0x7fffu + ((u>>16)&1u);          // RNE
  return (ushort)(u>>16);
}
__device__ __forceinline__ float bf2f(ushort s){
  uint u = ((uint)s)<<16; return __builtin_bit_cast(float, u);
}
// acc[0..7] += w * unpack8(bf16x8 in uint4)  (feature order: low16 first)
__device__ __forceinline__ void fma8(float* acc, uint4 g, float w){
  uint u[4] = {g.x, g.y, g.z, g.w};
  #pragma unroll
  for (int q=0;q<4;q++){
    float lo = __builtin_bit_cast(float, u[q]<<16);
    float hi = __builtin_bit_cast(float, u[q] & 0xffff0000u);
    acc[2*q]   += w*lo;
    acc[2*q+1] += w*hi;
  }
}
__device__ __forceinline__ uint4 pack8(const float* a){
  uint4 o;
  o.x = (uint)f2bf(a[0]) | ((uint)f2bf(a[1])<<16);
  o.y = (uint)f2bf(a[2]) | ((uint)f2bf(a[3])<<16);
  o.z = (uint)f2bf(a[4]) | ((uint)f2bf(a[5])<<16);
  o.w = (uint)f2bf(a[6]) | ((uint)f2bf(a[7])<<16);
  return o;
}

// ---------------- fp32 -> bf16 elementwise ----------------
__global__ __launch_bounds__(256) void tobf(const float* __restrict__ X, ushort* __restrict__ Xb){
  int i = blockIdx.x*256 + threadIdx.x;
  Xb[i] = f2bf(X[i]);
}

// ---------------- batched 512x512 transpose -> bf16: W[b][r][c] -> T[b][c][r] ----------------
__global__ __launch_bounds__(256) void tbf(const float* __restrict__ W, ushort* __restrict__ T){
  __shared__ float tile[32][33];
  int b = blockIdx.z;
  int r0 = blockIdx.y*32, c0 = blockIdx.x*32;
  int t = threadIdx.x;
  int i = t>>3, j0 = (t&7)*4;
  const float* Wb = W + (size_t)b*512*512;
  float4 v = *(const float4*)(Wb + (size_t)(r0+i)*512 + c0 + j0);
  tile[i][j0]=v.x; tile[i][j0+1]=v.y; tile[i][j0+2]=v.z; tile[i][j0+3]=v.w;
  __syncthreads();
  ushort* o = T + (size_t)b*512*512 + (size_t)(c0+i)*512 + r0 + j0;
  #pragma unroll
  for (int q=0;q<4;q++) o[q] = f2bf(tile[j0+q][i]);
}

// ---------------- bf16 MFMA GEMM: C = A@B^T, 128x128 tile ----------------
// A row-major [M][K]; B stored TRANSPOSED [N][K]. Both bf16.
// relu_res: C = relu(AB)+Res. Cf (fp32) and Cb (bf16) optional outputs.
__global__ __launch_bounds__(256) void gemm_bf(
    const ushort* __restrict__ A, const ushort* __restrict__ B,
    const float* __restrict__ Res, float* __restrict__ Cf, ushort* __restrict__ Cb,
    int M, int N, int K, int relu_res)
{
  __shared__ __align__(16) ushort Ah[128*LDA];
  __shared__ __align__(16) ushort Bh[128*LDA];
  int t = threadIdx.x;
  int m0 = blockIdx.y*128, n0 = blockIdx.x*128;
  int srow = t>>1, scol = (t&1)*16;              // stage: 2 threads/row, 16 shorts each
  int wave = t>>6, lane = t&63;
  int wm = (wave&1)*64, wn = (wave>>1)*64;
  int lm = lane&15, quad = lane>>4;

  ffrag acc[4][4];
  #pragma unroll
  for (int i=0;i<4;i++){
    #pragma unroll
    for (int j=0;j<4;j++) acc[i][j] = (ffrag){0.f,0.f,0.f,0.f};
  }

  const ushort* pA = A + (size_t)(m0+srow)*K + scol;
  const ushort* pB = B + (size_t)(n0+srow)*K + scol;

  uint4 ra0 = *(const uint4*)(pA);  uint4 ra1 = *(const uint4*)(pA+8);
  uint4 rb0 = *(const uint4*)(pB);  uint4 rb1 = *(const uint4*)(pB+8);

  int sidx = srow*LDA + scol;
  for (int k0 = 0; k0 < K; k0 += 32){
    __syncthreads();
    *(uint4*)&Ah[sidx] = ra0; *(uint4*)&Ah[sidx+8] = ra1;
    *(uint4*)&Bh[sidx] = rb0; *(uint4*)&Bh[sidx+8] = rb1;
    __syncthreads();
    if (k0+32 < K){
      ra0 = *(const uint4*)(pA+k0+32); ra1 = *(const uint4*)(pA+k0+40);
      rb0 = *(const uint4*)(pB+k0+32); rb1 = *(const uint4*)(pB+k0+40);
    }
    bfrag af[4];
    #pragma unroll
    for (int mt=0; mt<4; mt++)
      af[mt] = *(const bfrag*)&Ah[(wm+mt*16+lm)*LDA + quad*8];
    #pragma unroll
    for (int nt=0; nt<4; nt++){
      bfrag bf = *(const bfrag*)&Bh[(wn+nt*16+lm)*LDA + quad*8];
      #pragma unroll
      for (int mt=0; mt<4; mt++)
        acc[mt][nt] = __builtin_amdgcn_mfma_f32_16x16x32_bf16(af[mt], bf, acc[mt][nt], 0,0,0);
    }
  }

  #pragma unroll
  for (int mt=0; mt<4; mt++){
    #pragma unroll
    for (int nt=0; nt<4; nt++){
      #pragma unroll
      for (int r=0;r<4;r++){
        int grow = m0 + wm + mt*16 + quad*4 + r;
        int gcol = n0 + wn + nt*16 + lm;
        size_t off = (size_t)grow*N + gcol;
        float v = acc[mt][nt][r];
        if (relu_res) v = fmaxf(v,0.f) + Res[off];
        if (Cf) Cf[off] = v;
        if (Cb) Cb[off] = f2bf(v);
      }
    }
  }
}

// ---------------- attention logits per (node,head), bf16 h, uint4 loads ----------------
__global__ __launch_bounds__(256) void compute_lg(const ushort* __restrict__ hbf,
    const float* __restrict__ a_src, const float* __restrict__ a_dst,
    float* __restrict__ lgs, float* __restrict__ lgd){
  int n = blockIdx.x; int t = threadIdx.x;
  int hd = t>>6, lane = t&63;
  uint4 g = *(const uint4*)(hbf + (size_t)n*FW + hd*HIDC + lane*8);
  float h[8] = {0,0,0,0,0,0,0,0};
  fma8(h, g, 1.0f);
  const float* as = a_src + hd*HIDC + lane*8;
  const float* ad = a_dst + hd*HIDC + lane*8;
  float s1=0.f, s2=0.f;
  #pragma unroll
  for (int q=0;q<8;q++){ s1 += h[q]*as[q]; s2 += h[q]*ad[q]; }
  for (int off=32; off; off>>=1){ s1 += __shfl_down(s1,off); s2 += __shfl_down(s2,off); }
  if (lane==0){ lgs[n*HEADS+hd]=s1; lgd[n*HEADS+hd]=s2; }
}

// ---------------- CSR build helpers ----------------
__global__ __launch_bounds__(256) void hist_dst(const int* __restrict__ dst, int* __restrict__ indeg){
  int e = blockIdx.x*256+threadIdx.x; if (e<Ee) atomicAdd(&indeg[dst[e]],1);
}
__global__ __launch_bounds__(1024) void exscan(const int* __restrict__ cnt, int* __restrict__ rowptr, int n){
  __shared__ int sums[1024];
  int t = threadIdx.x;
  int v[4]; int s=0;
  #pragma unroll
  for (int i=0;i<4;i++){ int idx=t*4+i; v[i] = (idx<n)? cnt[idx] : 0; s+=v[i]; }
  sums[t]=s; __syncthreads();
  for (int off=1; off<1024; off<<=1){
    int other = (t>=off)? sums[t-off] : 0;
    __syncthreads();
    sums[t] += other;
    __syncthreads();
  }
  int run = (t>0)? sums[t-1] : 0;
  #pragma unroll
  for (int i=0;i<4;i++){ int idx=t*4+i; if (idx<n) rowptr[idx]=run; run+=v[i]; }
  if (t==1023) rowptr[n]=sums[1023];
}
// store SRC VALUE directly (not edge id) in dst-CSR
__global__ __launch_bounds__(256) void scatter_dst(const int* __restrict__ src, const int* __restrict__ dst,
    const int* __restrict__ rowptr, int* __restrict__ fill, int* __restrict__ slist){
  int e = blockIdx.x*256+threadIdx.x; if (e>=Ee) return;
  int d = dst[e]; int p = atomicAdd(&fill[d],1); slist[rowptr[d]+p]=src[e];
}
__global__ __launch_bounds__(256) void dedup_mark(const int* __restrict__ src, const int* __restrict__ dst,
    unsigned int* __restrict__ bitmap, int* __restrict__ cnt, int* __restrict__ flag){
  int e = blockIdx.x*256+threadIdx.x; if (e>=Ee) return;
  unsigned int key = (unsigned int)src[e]*Nn + (unsigned int)dst[e];
  unsigned int bit = 1u<<(key&31);
  unsigned int old = atomicOr(&bitmap[key>>5], bit);
  if (!(old & bit)){ flag[e]=1; atomicAdd(&cnt[src[e]],1); }
}
__global__ __launch_bounds__(256) void scatter_src(const int* __restrict__ src, const int* __restrict__ dst,
    const int* __restrict__ flag, const int* __restrict__ rowptr, int* __restrict__ fill, int* __restrict__ cols){
  int e = blockIdx.x*256+threadIdx.x; if (e>=Ee) return;
  if (!flag[e]) return;
  int s = src[e]; int p = atomicAdd(&fill[s],1); cols[rowptr[s]+p] = dst[e];
}
__global__ __launch_bounds__(256) void compute_dinv(const int* __restrict__ cnt, float* __restrict__ dinv){
  int n = blockIdx.x*256+threadIdx.x; if (n<Nn) dinv[n] = 1.0f/sqrtf((float)(1+cnt[n]));
}

// ---------------- GAT softmax-aggregate: block = node, wave = head ----------------
// 16B/lane gathers; alpha/src broadcast via shfl. Writes Hfeat fp32 + Hbf bf16.
__global__ __launch_bounds__(256) void gat_aggregate(const ushort* __restrict__ hbf,
    const float* __restrict__ lgs, const float* __restrict__ lgd,
    const int* __restrict__ rowptr, const int* __restrict__ slist,
    float* __restrict__ Hfeat, ushort* __restrict__ Hbf){
  int t = threadIdx.x;
  int hd = __builtin_amdgcn_readfirstlane(t>>6);
  int lane = t&63;
  int n = blockIdx.x;
  int beg = rowptr[n], deg = rowptr[n+1]-beg;
  float ldst = lgd[n*HEADS+hd];
  // pass 1: max
  float mx = -3.4e38f;
  for (int i=lane; i<deg; i+=64){
    float v = lgs[slist[beg+i]*HEADS+hd] + ldst;
    v = v>0.f ? v : 0.2f*v; mx = fmaxf(mx,v);
  }
  for (int o=32;o;o>>=1) mx = fmaxf(mx, __shfl_down(mx,o));
  mx = __shfl(mx,0);
  // pass 2: denom
  float zs = 0.f;
  for (int i=lane; i<deg; i+=64){
    float v = lgs[slist[beg+i]*HEADS+hd] + ldst;
    v = v>0.f ? v : 0.2f*v; zs += expf(v-mx);
  }
  for (int o=32;o;o>>=1) zs += __shfl_down(zs,o);
  zs = __shfl(zs,0);
  float inv = 1.f/(zs+1e-16f);
  // pass 3: weighted accumulate, 64-edge chunks
  float acc[8] = {0,0,0,0,0,0,0,0};
  for (int base=0; base<deg; base+=64){
    int i = base+lane;
    float al = 0.f; int s = 0;
    if (i<deg){
      s = slist[beg+i];
      float v = lgs[s*HEADS+hd] + ldst; v = v>0.f ? v : 0.2f*v;
      al = expf(v-mx)*inv;
    }
    int cn = min(64, deg-base);
    for (int c=0;c<cn;c++){
      float a = __shfl(al,c);
      int ss  = __shfl(s,c);
      uint4 g = *(const uint4*)(hbf + (size_t)ss*FW + hd*HIDC + lane*8);
      fma8(acc, g, a);
    }
  }
  size_t off = (size_t)n*FW + hd*HIDC + lane*8;
  *(float4*)(Hfeat + off)     = make_float4(acc[0],acc[1],acc[2],acc[3]);
  *(float4*)(Hfeat + off + 4) = make_float4(acc[4],acc[5],acc[6],acc[7]);
  *(uint4*)(Hbf + off) = pack8(acc);
}

// ---------------- SpMM: P = A_hat @ H, wave = (node, 512-chunk), 16B/lane ----------------
__global__ __launch_bounds__(256) void spmm_bf(const ushort* __restrict__ Hbf,
    ushort* __restrict__ Phi,
    const int* __restrict__ rowptr, const int* __restrict__ cols, const float* __restrict__ dinv){
  int t = threadIdx.x;
  int wv = __builtin_amdgcn_readfirstlane(t>>6);
  int lane = t&63;
  int n = blockIdx.x*4 + wv;
  int f = (blockIdx.y<<9) + lane*8;
  float di = dinv[n];
  float acc[8] = {0,0,0,0,0,0,0,0};
  uint4 self = *(const uint4*)(Hbf + (size_t)n*FW + f);
  fma8(acc, self, di*di);
  int beg = rowptr[n], end = rowptr[n+1];
  for (int base=beg; base<end; base+=64){
    int i = base + lane;
    int m = n; float w = 0.f;
    if (i < end){ m = cols[i]; w = di*dinv[m]; }
    int cn = min(64, end-base);
    for (int c=0;c<cn;c++){
      int mm   = __shfl(m,c);
      float ww = __shfl(w,c);
      uint4 g = *(const uint4*)(Hbf + (size_t)mm*FW + f);
      fma8(acc, g, ww);
    }
  }
  *(uint4*)(Phi + (size_t)n*FW + f) = pack8(acc);
}

// ---------------- pooling ----------------
__global__ __launch_bounds__(256) void graph_offsets(const int* __restrict__ batch, int* __restrict__ goff){
  __shared__ int cnt[GG];
  int t = threadIdx.x;
  if (t<GG) cnt[t]=0;
  __syncthreads();
  for (int i=t;i<Nn;i+=256) atomicAdd(&cnt[batch[i]],1);
  __syncthreads();
  if (t==0){ int run=0; for (int g=0; g<GG; g++){ goff[g]=run; run+=cnt[g]; } goff[GG]=run; }
}
__global__ __launch_bounds__(256) void pool_mean(const float* __restrict__ H, const int* __restrict__ goff,
    float* __restrict__ pooled){
  int g = blockIdx.x; int d = blockIdx.y*256 + threadIdx.x;
  int beg=goff[g], end=goff[g+1];
  float s=0.f;
  for (int n=beg;n<end;n++) s += H[(size_t)n*FW + d];
  pooled[(size_t)g*FW + d] = s / fmaxf((float)(end-beg), 1.f);
}
__global__ __launch_bounds__(256) void final_out(const float* __restrict__ pooled,
    const float* __restrict__ fc_w, const float* __restrict__ fc_b, float* __restrict__ out){
  int g = blockIdx.x; int t = threadIdx.x;
  float p = 0.f;
  for (int d=t; d<HIDC; d+=256){
    float f = 0.25f*(pooled[(size_t)g*FW+d] + pooled[(size_t)g*FW+HIDC+d]
                   + pooled[(size_t)g*FW+2*HIDC+d] + pooled[(size_t)g*FW+3*HIDC+d]);
    p += f*fc_w[d];
  }
  __shared__ float red[4];
  for (int off=32; off; off>>=1) p += __shfl_down(p,off);
  if ((t&63)==0) red[t>>6]=p;
  __syncthreads();
  if (t==0) out[g] = red[0]+red[1]+red[2]+red[3] + fc_b[0];
}

extern "C" void kernel_launch(void* const* d_in, const int* in_sizes, int n_in,
                              void* d_out, int out_size, void* d_ws, size_t ws_size,
                              hipStream_t stream){
  const float* x      = (const float*)d_in[0];
  const int*   ei     = (const int*)d_in[1];
  const int*   batch  = (const int*)d_in[2];
  const float* W_gat  = (const float*)d_in[3];
  const float* a_src  = (const float*)d_in[4];
  const float* a_dst  = (const float*)d_in[5];
  const float* W_gcn  = (const float*)d_in[6];
  const float* fc_w   = (const float*)d_in[7];
  const float* fc_b   = (const float*)d_in[8];
  float* out = (float*)d_out;
  const int* src = ei;
  const int* dst = ei + Ee;

  char* w = (char*)d_ws;
  size_t off = 0;
  auto alloc = [&](size_t bytes)->char*{ char* p = w + off; off = (off + bytes + 255) & ~(size_t)255; return p; };
  float*  Hfeat  = (float*)alloc((size_t)Nn*FW*4);        // fp32 node features (residual path)
  ushort* hbf    = (ushort*)alloc((size_t)Nn*FW*2);       // bf16 GAT projection; REUSED as Phi
  ushort* Hbf    = (ushort*)alloc((size_t)Nn*FW*2);       // bf16 copy of H for gathers
  ushort* Xbf    = (ushort*)alloc((size_t)Nn*INC*2);
  ushort* WgatT  = (ushort*)alloc((size_t)HEADS*INC*HIDC*2);
  ushort* WgcnT  = (ushort*)alloc((size_t)NLAY*HIDC*HIDC*2);
  float* lgs    = (float*)alloc((size_t)Nn*HEADS*4);
  float* lgd    = (float*)alloc((size_t)Nn*HEADS*4);
  int* indeg    = (int*)alloc(Nn*4);
  int* rowptr_d = (int*)alloc((Nn+1)*4);
  int* slist    = (int*)alloc(Ee*4);
  int* fill_d   = (int*)alloc(Nn*4);
  unsigned int* bitmap = (unsigned int*)alloc((size_t)Nn*Nn/8);
  int* cnt_s    = (int*)alloc(Nn*4);
  int* rowptr_s = (int*)alloc((Nn+1)*4);
  int* cols     = (int*)alloc(Ee*4);
  int* fill_s   = (int*)alloc(Nn*4);
  int* flag     = (int*)alloc(Ee*4);
  float* dinv   = (float*)alloc(Nn*4);
  float* pooled = (float*)alloc((size_t)GG*FW*4);
  int* goff     = (int*)alloc((GG+1)*4);
  ushort* Phi   = hbf;   // projection dead once GCN loop starts

  hipMemsetAsync(indeg, 0, Nn*4, stream);
  hipMemsetAsync(fill_d, 0, Nn*4, stream);
  hipMemsetAsync(cnt_s, 0, Nn*4, stream);
  hipMemsetAsync(fill_s, 0, Nn*4, stream);
  hipMemsetAsync(flag, 0, Ee*4, stream);
  hipMemsetAsync(bitmap, 0, (size_t)Nn*Nn/8, stream);

  // ---- input prep ----
  tobf<<<(Nn*INC)/256,256,0,stream>>>(x, Xbf);
  tbf<<<dim3(16,16,HEADS),256,0,stream>>>(W_gat, WgatT);
  tbf<<<dim3(16,16,NLAY),256,0,stream>>>(W_gcn, WgcnT);

  // ---- GAT projection (bf16 MFMA) ----
  gemm_bf<<<dim3(FW/128, Nn/128),256,0,stream>>>(Xbf, WgatT,
      nullptr, nullptr, hbf, Nn, FW, INC, 0);
  compute_lg<<<Nn,256,0,stream>>>(hbf, a_src, a_dst, lgs, lgd);

  // ---- CSR by dst for attention ----
  hist_dst<<<Ee/256,256,0,stream>>>(dst, indeg);
  exscan<<<1,1024,0,stream>>>(indeg, rowptr_d, Nn);
  scatter_dst<<<Ee/256,256,0,stream>>>(src, dst, rowptr_d, fill_d, slist);
  gat_aggregate<<<Nn,256,0,stream>>>(hbf, lgs, lgd, rowptr_d, slist, Hfeat, Hbf);

  // ---- dedup'd adjacency (set-semantics) + GCN normalization ----
  dedup_mark<<<Ee/256,256,0,stream>>>(src, dst, bitmap, cnt_s, flag);
  exscan<<<1,1024,0,stream>>>(cnt_s, rowptr_s, Nn);
  scatter_src<<<Ee/256,256,0,stream>>>(src, dst, flag, rowptr_s, fill_s, cols);
  compute_dinv<<<Nn/256,256,0,stream>>>(cnt_s, dinv);

  // ---- residual GCN layers ----
  for (int l=0;l<NLAY;l++){
    spmm_bf<<<dim3(Nn/4,4),256,0,stream>>>(Hbf, Phi, rowptr_s, cols, dinv);
    gemm_bf<<<dim3(HIDC/128, (Nn*HEADS)/128),256,0,stream>>>(Phi,
        WgcnT + (size_t)l*HIDC*HIDC,
        Hfeat, Hfeat, Hbf, Nn*HEADS, HIDC, HIDC, 1);
  }

  // ---- pooling + FC ----
  graph_offsets<<<1,256,0,stream>>>(batch, goff);
  pool_mean<<<dim3(GG, FW/256),256,0,stream>>>(Hfeat, goff, pooled);
  final_out<<<GG,256,0,stream>>>(pooled, fc_w, fc_b, out);
}

// Round 4
// 459.496 us; speedup vs baseline: 2.6606x; 1.2849x over previous
//
#include <hip/hip_runtime.h>
#include <cstdint>
#include <cstddef>

#define Nn    4096
#define Ee    131072
#define INC   512
#define HIDC  512
#define HEADS 4
#define NLAY  3
#define GG    16
#define FW    2048   // HEADS*HIDC
#define LDA   40     // padded LDS row stride (shorts) for 32-k tiles

typedef __attribute__((ext_vector_type(8))) short bfrag;   // 8 bf16 (4 VGPRs)
typedef __attribute__((ext_vector_type(4))) float ffrag;   // 4 fp32 acc

__device__ __forceinline__ ushort f2bf(float v){
  uint u = __builtin_bit_cast(uint, v);
  u += 0x7fffu + ((u>>16)&1u);          // RNE
  return (ushort)(u>>16);
}
__device__ __forceinline__ float bf2f(ushort s){
  uint u = ((uint)s)<<16; return __builtin_bit_cast(float, u);
}
// acc[0..7] += w * unpack8(bf16x8 in uint4)  (feature order: low16 first)
__device__ __forceinline__ void fma8(float* acc, uint4 g, float w){
  uint u[4] = {g.x, g.y, g.z, g.w};
  #pragma unroll
  for (int q=0;q<4;q++){
    float lo = __builtin_bit_cast(float, u[q]<<16);
    float hi = __builtin_bit_cast(float, u[q] & 0xffff0000u);
    acc[2*q]   += w*lo;
    acc[2*q+1] += w*hi;
  }
}
__device__ __forceinline__ uint4 pack8(const float* a){
  uint4 o;
  o.x = (uint)f2bf(a[0]) | ((uint)f2bf(a[1])<<16);
  o.y = (uint)f2bf(a[2]) | ((uint)f2bf(a[3])<<16);
  o.z = (uint)f2bf(a[4]) | ((uint)f2bf(a[5])<<16);
  o.w = (uint)f2bf(a[6]) | ((uint)f2bf(a[7])<<16);
  return o;
}

// ---------------- fp32 -> bf16 elementwise ----------------
__global__ __launch_bounds__(256) void tobf(const float* __restrict__ X, ushort* __restrict__ Xb){
  int i = blockIdx.x*256 + threadIdx.x;
  Xb[i] = f2bf(X[i]);
}

// ---------------- batched 512x512 transpose -> bf16: W[b][r][c] -> T[b][c][r] ----------------
__global__ __launch_bounds__(256) void tbf(const float* __restrict__ W, ushort* __restrict__ T){
  __shared__ float tile[32][33];
  int b = blockIdx.z;
  int r0 = blockIdx.y*32, c0 = blockIdx.x*32;
  int t = threadIdx.x;
  int i = t>>3, j0 = (t&7)*4;
  const float* Wb = W + (size_t)b*512*512;
  float4 v = *(const float4*)(Wb + (size_t)(r0+i)*512 + c0 + j0);
  tile[i][j0]=v.x; tile[i][j0+1]=v.y; tile[i][j0+2]=v.z; tile[i][j0+3]=v.w;
  __syncthreads();
  ushort* o = T + (size_t)b*512*512 + (size_t)(c0+i)*512 + r0 + j0;
  #pragma unroll
  for (int q=0;q<4;q++) o[q] = f2bf(tile[j0+q][i]);
}

// ---------------- bf16 MFMA GEMM: C = A@B^T, 128x128 tile ----------------
__global__ __launch_bounds__(256) void gemm_bf(
    const ushort* __restrict__ A, const ushort* __restrict__ B,
    const float* __restrict__ Res, float* __restrict__ Cf, ushort* __restrict__ Cb,
    int M, int N, int K, int relu_res)
{
  __shared__ __align__(16) ushort Ah[128*LDA];
  __shared__ __align__(16) ushort Bh[128*LDA];
  int t = threadIdx.x;
  int m0 = blockIdx.y*128, n0 = blockIdx.x*128;
  int srow = t>>1, scol = (t&1)*16;
  int wave = t>>6, lane = t&63;
  int wm = (wave&1)*64, wn = (wave>>1)*64;
  int lm = lane&15, quad = lane>>4;

  ffrag acc[4][4];
  #pragma unroll
  for (int i=0;i<4;i++){
    #pragma unroll
    for (int j=0;j<4;j++) acc[i][j] = (ffrag){0.f,0.f,0.f,0.f};
  }

  const ushort* pA = A + (size_t)(m0+srow)*K + scol;
  const ushort* pB = B + (size_t)(n0+srow)*K + scol;

  uint4 ra0 = *(const uint4*)(pA);  uint4 ra1 = *(const uint4*)(pA+8);
  uint4 rb0 = *(const uint4*)(pB);  uint4 rb1 = *(const uint4*)(pB+8);

  int sidx = srow*LDA + scol;
  for (int k0 = 0; k0 < K; k0 += 32){
    __syncthreads();
    *(uint4*)&Ah[sidx] = ra0; *(uint4*)&Ah[sidx+8] = ra1;
    *(uint4*)&Bh[sidx] = rb0; *(uint4*)&Bh[sidx+8] = rb1;
    __syncthreads();
    if (k0+32 < K){
      ra0 = *(const uint4*)(pA+k0+32); ra1 = *(const uint4*)(pA+k0+40);
      rb0 = *(const uint4*)(pB+k0+32); rb1 = *(const uint4*)(pB+k0+40);
    }
    bfrag af[4];
    #pragma unroll
    for (int mt=0; mt<4; mt++)
      af[mt] = *(const bfrag*)&Ah[(wm+mt*16+lm)*LDA + quad*8];
    #pragma unroll
    for (int nt=0; nt<4; nt++){
      bfrag bf = *(const bfrag*)&Bh[(wn+nt*16+lm)*LDA + quad*8];
      #pragma unroll
      for (int mt=0; mt<4; mt++)
        acc[mt][nt] = __builtin_amdgcn_mfma_f32_16x16x32_bf16(af[mt], bf, acc[mt][nt], 0,0,0);
    }
  }

  #pragma unroll
  for (int mt=0; mt<4; mt++){
    #pragma unroll
    for (int nt=0; nt<4; nt++){
      #pragma unroll
      for (int r=0;r<4;r++){
        int grow = m0 + wm + mt*16 + quad*4 + r;
        int gcol = n0 + wn + nt*16 + lm;
        size_t off = (size_t)grow*N + gcol;
        float v = acc[mt][nt][r];
        if (relu_res) v = fmaxf(v,0.f) + Res[off];
        if (Cf) Cf[off] = v;
        if (Cb) Cb[off] = f2bf(v);
      }
    }
  }
}

// ---------------- attention logits per (node,head) ----------------
__global__ __launch_bounds__(256) void compute_lg(const ushort* __restrict__ hbf,
    const float* __restrict__ a_src, const float* __restrict__ a_dst,
    float* __restrict__ lgs, float* __restrict__ lgd){
  int n = blockIdx.x; int t = threadIdx.x;
  int hd = t>>6, lane = t&63;
  uint4 g = *(const uint4*)(hbf + (size_t)n*FW + hd*HIDC + lane*8);
  float h[8] = {0,0,0,0,0,0,0,0};
  fma8(h, g, 1.0f);
  float4 as0 = *(const float4*)(a_src + hd*HIDC + lane*8);
  float4 as1 = *(const float4*)(a_src + hd*HIDC + lane*8 + 4);
  float4 ad0 = *(const float4*)(a_dst + hd*HIDC + lane*8);
  float4 ad1 = *(const float4*)(a_dst + hd*HIDC + lane*8 + 4);
  float s1 = h[0]*as0.x + h[1]*as0.y + h[2]*as0.z + h[3]*as0.w
           + h[4]*as1.x + h[5]*as1.y + h[6]*as1.z + h[7]*as1.w;
  float s2 = h[0]*ad0.x + h[1]*ad0.y + h[2]*ad0.z + h[3]*ad0.w
           + h[4]*ad1.x + h[5]*ad1.y + h[6]*ad1.z + h[7]*ad1.w;
  for (int off=32; off; off>>=1){ s1 += __shfl_down(s1,off); s2 += __shfl_down(s2,off); }
  if (lane==0){ lgs[n*HEADS+hd]=s1; lgd[n*HEADS+hd]=s2; }
}

// ---------------- CSR build helpers ----------------
__global__ __launch_bounds__(256) void hist_dst(const int* __restrict__ dst, int* __restrict__ indeg){
  int e = blockIdx.x*256+threadIdx.x; if (e<Ee) atomicAdd(&indeg[dst[e]],1);
}
__global__ __launch_bounds__(1024) void exscan(const int* __restrict__ cnt, int* __restrict__ rowptr, int n){
  __shared__ int sums[1024];
  int t = threadIdx.x;
  int v[4]; int s=0;
  #pragma unroll
  for (int i=0;i<4;i++){ int idx=t*4+i; v[i] = (idx<n)? cnt[idx] : 0; s+=v[i]; }
  sums[t]=s; __syncthreads();
  for (int off=1; off<1024; off<<=1){
    int other = (t>=off)? sums[t-off] : 0;
    __syncthreads();
    sums[t] += other;
    __syncthreads();
  }
  int run = (t>0)? sums[t-1] : 0;
  #pragma unroll
  for (int i=0;i<4;i++){ int idx=t*4+i; if (idx<n) rowptr[idx]=run; run+=v[i]; }
  if (t==1023) rowptr[n]=sums[1023];
}
__global__ __launch_bounds__(256) void scatter_dst(const int* __restrict__ src, const int* __restrict__ dst,
    const int* __restrict__ rowptr, int* __restrict__ fill, int* __restrict__ slist){
  int e = blockIdx.x*256+threadIdx.x; if (e>=Ee) return;
  int d = dst[e]; int p = atomicAdd(&fill[d],1); slist[rowptr[d]+p]=src[e];
}
__global__ __launch_bounds__(256) void dedup_mark(const int* __restrict__ src, const int* __restrict__ dst,
    unsigned int* __restrict__ bitmap, int* __restrict__ cnt, int* __restrict__ flag){
  int e = blockIdx.x*256+threadIdx.x; if (e>=Ee) return;
  unsigned int key = (unsigned int)src[e]*Nn + (unsigned int)dst[e];
  unsigned int bit = 1u<<(key&31);
  unsigned int old = atomicOr(&bitmap[key>>5], bit);
  if (!(old & bit)){ flag[e]=1; atomicAdd(&cnt[src[e]],1); }
}
__global__ __launch_bounds__(256) void scatter_src(const int* __restrict__ src, const int* __restrict__ dst,
    const int* __restrict__ flag, const int* __restrict__ rowptr, int* __restrict__ fill, int* __restrict__ cols){
  int e = blockIdx.x*256+threadIdx.x; if (e>=Ee) return;
  if (!flag[e]) return;
  int s = src[e]; int p = atomicAdd(&fill[s],1); cols[rowptr[s]+p] = dst[e];
}
__global__ __launch_bounds__(256) void compute_dinv(const int* __restrict__ cnt, float* __restrict__ dinv){
  int n = blockIdx.x*256+threadIdx.x; if (n<Nn) dinv[n] = 1.0f/sqrtf((float)(1+cnt[n]));
}

// ---------------- GAT softmax-aggregate: block = (4 nodes) x (1 head), wave = node ----------------
// head = blockIdx.x & 3  =>  XCD b%8 sees one 4MB head slice (L2 locality).
__global__ __launch_bounds__(256) void gat_aggregate(const ushort* __restrict__ hbf,
    const float* __restrict__ lgs, const float* __restrict__ lgd,
    const int* __restrict__ rowptr, const int* __restrict__ slist,
    float* __restrict__ Hfeat, ushort* __restrict__ Hbf){
  int t = threadIdx.x;
  int wv = __builtin_amdgcn_readfirstlane(t>>6);
  int lane = t&63;
  int b = blockIdx.x;
  int hd = __builtin_amdgcn_readfirstlane(b & 3);
  int n = ((b>>2)<<2) + wv;
  int beg = rowptr[n], deg = rowptr[n+1]-beg;
  float ldst = lgd[n*HEADS+hd];
  // pass 1: max
  float mx = -3.4e38f;
  for (int i=lane; i<deg; i+=64){
    float v = lgs[slist[beg+i]*HEADS+hd] + ldst;
    v = v>0.f ? v : 0.2f*v; mx = fmaxf(mx,v);
  }
  for (int o=32;o;o>>=1) mx = fmaxf(mx, __shfl_down(mx,o));
  mx = __shfl(mx,0);
  // pass 2: denom
  float zs = 0.f;
  for (int i=lane; i<deg; i+=64){
    float v = lgs[slist[beg+i]*HEADS+hd] + ldst;
    v = v>0.f ? v : 0.2f*v; zs += expf(v-mx);
  }
  for (int o=32;o;o>>=1) zs += __shfl_down(zs,o);
  zs = __shfl(zs,0);
  float inv = 1.f/(zs+1e-16f);
  // pass 3: weighted accumulate, 64-edge chunks
  float acc[8] = {0,0,0,0,0,0,0,0};
  for (int base=0; base<deg; base+=64){
    int i = base+lane;
    float al = 0.f; int s = 0;
    if (i<deg){
      s = slist[beg+i];
      float v = lgs[s*HEADS+hd] + ldst; v = v>0.f ? v : 0.2f*v;
      al = expf(v-mx)*inv;
    }
    int cn = min(64, deg-base);
    #pragma unroll 4
    for (int c=0;c<cn;c++){
      float a = __shfl(al,c);
      int ss  = __shfl(s,c);
      uint4 g = *(const uint4*)(hbf + (size_t)ss*FW + hd*HIDC + lane*8);
      fma8(acc, g, a);
    }
  }
  size_t off = (size_t)n*FW + hd*HIDC + lane*8;
  *(float4*)(Hfeat + off)     = make_float4(acc[0],acc[1],acc[2],acc[3]);
  *(float4*)(Hfeat + off + 4) = make_float4(acc[4],acc[5],acc[6],acc[7]);
  *(uint4*)(Hbf + off) = pack8(acc);
}

// ---------------- SpMM: block = (4 nodes) x (1 chunk), chunk = blockIdx.x & 3 ----------------
__global__ __launch_bounds__(256) void spmm_bf(const ushort* __restrict__ Hbf,
    ushort* __restrict__ Phi,
    const int* __restrict__ rowptr, const int* __restrict__ cols, const float* __restrict__ dinv){
  int t = threadIdx.x;
  int wv = __builtin_amdgcn_readfirstlane(t>>6);
  int lane = t&63;
  int b = blockIdx.x;
  int ck = __builtin_amdgcn_readfirstlane(b & 3);
  int n = ((b>>2)<<2) + wv;
  int f = (ck<<9) + lane*8;
  float di = dinv[n];
  float acc[8] = {0,0,0,0,0,0,0,0};
  uint4 self = *(const uint4*)(Hbf + (size_t)n*FW + f);
  fma8(acc, self, di*di);
  int beg = rowptr[n], end = rowptr[n+1];
  for (int base=beg; base<end; base+=64){
    int i = base + lane;
    int m = n; float w = 0.f;
    if (i < end){ m = cols[i]; w = di*dinv[m]; }
    int cn = min(64, end-base);
    #pragma unroll 4
    for (int c=0;c<cn;c++){
      int mm   = __shfl(m,c);
      float ww = __shfl(w,c);
      uint4 g = *(const uint4*)(Hbf + (size_t)mm*FW + f);
      fma8(acc, g, ww);
    }
  }
  *(uint4*)(Phi + (size_t)n*FW + f) = pack8(acc);
}

// ---------------- pooling ----------------
__global__ __launch_bounds__(256) void graph_offsets(const int* __restrict__ batch, int* __restrict__ goff){
  __shared__ int cnt[GG];
  int t = threadIdx.x;
  if (t<GG) cnt[t]=0;
  __syncthreads();
  for (int i=t;i<Nn;i+=256) atomicAdd(&cnt[batch[i]],1);
  __syncthreads();
  if (t==0){ int run=0; for (int g=0; g<GG; g++){ goff[g]=run; run+=cnt[g]; } goff[GG]=run; }
}
// segmented sum into psum[G][FW] via atomics; batch is sorted
__global__ __launch_bounds__(256) void pool_accum(const float* __restrict__ H,
    const int* __restrict__ batch, float* __restrict__ psum){
  int d = blockIdx.y*256 + threadIdx.x;
  int n0 = blockIdx.x*32;
  int g = batch[n0];
  float s = 0.f;
  for (int k=0;k<32;k++){
    int n = n0+k;
    int gn = batch[n];
    if (gn != g){ atomicAdd(&psum[(size_t)g*FW+d], s); s=0.f; g=gn; }
    s += H[(size_t)n*FW + d];
  }
  atomicAdd(&psum[(size_t)g*FW+d], s);
}
__global__ __launch_bounds__(256) void final_out(const float* __restrict__ psum,
    const int* __restrict__ goff,
    const float* __restrict__ fc_w, const float* __restrict__ fc_b, float* __restrict__ out){
  int g = blockIdx.x; int t = threadIdx.x;
  float cinv = 0.25f / fmaxf((float)(goff[g+1]-goff[g]), 1.f);
  float p = 0.f;
  for (int d=t; d<HIDC; d+=256){
    float f = cinv*(psum[(size_t)g*FW+d] + psum[(size_t)g*FW+HIDC+d]
                  + psum[(size_t)g*FW+2*HIDC+d] + psum[(size_t)g*FW+3*HIDC+d]);
    p += f*fc_w[d];
  }
  __shared__ float red[4];
  for (int off=32; off; off>>=1) p += __shfl_down(p,off);
  if ((t&63)==0) red[t>>6]=p;
  __syncthreads();
  if (t==0) out[g] = red[0]+red[1]+red[2]+red[3] + fc_b[0];
}

extern "C" void kernel_launch(void* const* d_in, const int* in_sizes, int n_in,
                              void* d_out, int out_size, void* d_ws, size_t ws_size,
                              hipStream_t stream){
  const float* x      = (const float*)d_in[0];
  const int*   ei     = (const int*)d_in[1];
  const int*   batch  = (const int*)d_in[2];
  const float* W_gat  = (const float*)d_in[3];
  const float* a_src  = (const float*)d_in[4];
  const float* a_dst  = (const float*)d_in[5];
  const float* W_gcn  = (const float*)d_in[6];
  const float* fc_w   = (const float*)d_in[7];
  const float* fc_b   = (const float*)d_in[8];
  float* out = (float*)d_out;
  const int* src = ei;
  const int* dst = ei + Ee;

  char* w = (char*)d_ws;
  size_t off = 0;
  auto alloc = [&](size_t bytes)->char*{ char* p = w + off; off = (off + bytes + 255) & ~(size_t)255; return p; };
  float*  Hfeat  = (float*)alloc((size_t)Nn*FW*4);
  ushort* hbf    = (ushort*)alloc((size_t)Nn*FW*2);       // GAT projection; REUSED as Phi
  ushort* Hbf    = (ushort*)alloc((size_t)Nn*FW*2);
  ushort* Xbf    = (ushort*)alloc((size_t)Nn*INC*2);
  ushort* WgatT  = (ushort*)alloc((size_t)HEADS*INC*HIDC*2);
  ushort* WgcnT  = (ushort*)alloc((size_t)NLAY*HIDC*HIDC*2);
  float* lgs    = (float*)alloc((size_t)Nn*HEADS*4);
  float* lgd    = (float*)alloc((size_t)Nn*HEADS*4);
  int* indeg    = (int*)alloc(Nn*4);
  int* rowptr_d = (int*)alloc((Nn+1)*4);
  int* slist    = (int*)alloc(Ee*4);
  int* fill_d   = (int*)alloc(Nn*4);
  unsigned int* bitmap = (unsigned int*)alloc((size_t)Nn*Nn/8);
  int* cnt_s    = (int*)alloc(Nn*4);
  int* rowptr_s = (int*)alloc((Nn+1)*4);
  int* cols     = (int*)alloc(Ee*4);
  int* fill_s   = (int*)alloc(Nn*4);
  int* flag     = (int*)alloc(Ee*4);
  float* dinv   = (float*)alloc(Nn*4);
  float* psum   = (float*)alloc((size_t)GG*FW*4);
  int* goff     = (int*)alloc((GG+1)*4);
  ushort* Phi   = hbf;

  hipMemsetAsync(indeg, 0, Nn*4, stream);
  hipMemsetAsync(fill_d, 0, Nn*4, stream);
  hipMemsetAsync(cnt_s, 0, Nn*4, stream);
  hipMemsetAsync(fill_s, 0, Nn*4, stream);
  hipMemsetAsync(flag, 0, Ee*4, stream);
  hipMemsetAsync(bitmap, 0, (size_t)Nn*Nn/8, stream);
  hipMemsetAsync(psum, 0, (size_t)GG*FW*4, stream);

  // ---- input prep ----
  tobf<<<(Nn*INC)/256,256,0,stream>>>(x, Xbf);
  tbf<<<dim3(16,16,HEADS),256,0,stream>>>(W_gat, WgatT);
  tbf<<<dim3(16,16,NLAY),256,0,stream>>>(W_gcn, WgcnT);

  // ---- GAT projection (bf16 MFMA) ----
  gemm_bf<<<dim3(FW/128, Nn/128),256,0,stream>>>(Xbf, WgatT,
      nullptr, nullptr, hbf, Nn, FW, INC, 0);
  compute_lg<<<Nn,256,0,stream>>>(hbf, a_src, a_dst, lgs, lgd);

  // ---- CSR by dst for attention ----
  hist_dst<<<Ee/256,256,0,stream>>>(dst, indeg);
  exscan<<<1,1024,0,stream>>>(indeg, rowptr_d, Nn);
  scatter_dst<<<Ee/256,256,0,stream>>>(src, dst, rowptr_d, fill_d, slist);
  gat_aggregate<<<Nn,256,0,stream>>>(hbf, lgs, lgd, rowptr_d, slist, Hfeat, Hbf);

  // ---- dedup'd adjacency (set-semantics) + GCN normalization ----
  dedup_mark<<<Ee/256,256,0,stream>>>(src, dst, bitmap, cnt_s, flag);
  exscan<<<1,1024,0,stream>>>(cnt_s, rowptr_s, Nn);
  scatter_src<<<Ee/256,256,0,stream>>>(src, dst, flag, rowptr_s, fill_s, cols);
  compute_dinv<<<Nn/256,256,0,stream>>>(cnt_s, dinv);

  // ---- residual GCN layers ----
  for (int l=0;l<NLAY;l++){
    spmm_bf<<<Nn,256,0,stream>>>(Hbf, Phi, rowptr_s, cols, dinv);
    gemm_bf<<<dim3(HIDC/128, (Nn*HEADS)/128),256,0,stream>>>(Phi,
        WgcnT + (size_t)l*HIDC*HIDC,
        Hfeat, Hfeat, (l==NLAY-1)? nullptr : Hbf, Nn*HEADS, HIDC, HIDC, 1);
  }

  // ---- pooling + FC ----
  graph_offsets<<<1,256,0,stream>>>(batch, goff);
  pool_accum<<<dim3(Nn/32, FW/256),256,0,stream>>>(Hfeat, batch, psum);
  final_out<<<GG,256,0,stream>>>(psum, goff, fc_w, fc_b, out);
}

// Round 5
// 424.844 us; speedup vs baseline: 2.8776x; 1.0816x over previous
//
#include <hip/hip_runtime.h>
#include <cstdint>
#include <cstddef>

#define Nn    4096
#define Ee    131072
#define INC   512
#define HIDC  512
#define HEADS 4
#define NLAY  3
#define GG    16
#define FW    2048   // HEADS*HIDC
#define LDA   40     // padded LDS row stride (shorts) for 32-k tiles

typedef __attribute__((ext_vector_type(8))) short bfrag;   // 8 bf16 (4 VGPRs)
typedef __attribute__((ext_vector_type(4))) float ffrag;   // 4 fp32 acc

__device__ __forceinline__ ushort f2bf(float v){
  uint u = __builtin_bit_cast(uint, v);
  u += 0x7fffu + ((u>>16)&1u);          // RNE
  return (ushort)(u>>16);
}
__device__ __forceinline__ float bf2f(ushort s){
  uint u = ((uint)s)<<16; return __builtin_bit_cast(float, u);
}
// acc[0..7] += w * unpack8(bf16x8 in uint4)  (feature order: low16 first)
__device__ __forceinline__ void fma8(float* acc, uint4 g, float w){
  uint u[4] = {g.x, g.y, g.z, g.w};
  #pragma unroll
  for (int q=0;q<4;q++){
    float lo = __builtin_bit_cast(float, u[q]<<16);
    float hi = __builtin_bit_cast(float, u[q] & 0xffff0000u);
    acc[2*q]   += w*lo;
    acc[2*q+1] += w*hi;
  }
}
__device__ __forceinline__ uint4 pack8(const float* a){
  uint4 o;
  o.x = (uint)f2bf(a[0]) | ((uint)f2bf(a[1])<<16);
  o.y = (uint)f2bf(a[2]) | ((uint)f2bf(a[3])<<16);
  o.z = (uint)f2bf(a[4]) | ((uint)f2bf(a[5])<<16);
  o.w = (uint)f2bf(a[6]) | ((uint)f2bf(a[7])<<16);
  return o;
}

// ---------------- fp32 -> bf16 elementwise ----------------
__global__ __launch_bounds__(256) void tobf(const float* __restrict__ X, ushort* __restrict__ Xb){
  int i = blockIdx.x*256 + threadIdx.x;
  Xb[i] = f2bf(X[i]);
}

// ---------------- batched 512x512 transpose -> bf16: W[b][r][c] -> T[b][c][r] ----------------
__global__ __launch_bounds__(256) void tbf(const float* __restrict__ W, ushort* __restrict__ T){
  __shared__ float tile[32][33];
  int b = blockIdx.z;
  int r0 = blockIdx.y*32, c0 = blockIdx.x*32;
  int t = threadIdx.x;
  int i = t>>3, j0 = (t&7)*4;
  const float* Wb = W + (size_t)b*512*512;
  float4 v = *(const float4*)(Wb + (size_t)(r0+i)*512 + c0 + j0);
  tile[i][j0]=v.x; tile[i][j0+1]=v.y; tile[i][j0+2]=v.z; tile[i][j0+3]=v.w;
  __syncthreads();
  ushort* o = T + (size_t)b*512*512 + (size_t)(c0+i)*512 + r0 + j0;
  #pragma unroll
  for (int q=0;q<4;q++) o[q] = f2bf(tile[j0+q][i]);
}

// ---------------- bf16 MFMA GEMM: C = A@B^T, 128x128 tile ----------------
__global__ __launch_bounds__(256) void gemm_bf(
    const ushort* __restrict__ A, const ushort* __restrict__ B,
    const float* __restrict__ Res, float* __restrict__ Cf, ushort* __restrict__ Cb,
    int M, int N, int K, int relu_res)
{
  __shared__ __align__(16) ushort Ah[128*LDA];
  __shared__ __align__(16) ushort Bh[128*LDA];
  int t = threadIdx.x;
  int m0 = blockIdx.y*128, n0 = blockIdx.x*128;
  int srow = t>>1, scol = (t&1)*16;
  int wave = t>>6, lane = t&63;
  int wm = (wave&1)*64, wn = (wave>>1)*64;
  int lm = lane&15, quad = lane>>4;

  ffrag acc[4][4];
  #pragma unroll
  for (int i=0;i<4;i++){
    #pragma unroll
    for (int j=0;j<4;j++) acc[i][j] = (ffrag){0.f,0.f,0.f,0.f};
  }

  const ushort* pA = A + (size_t)(m0+srow)*K + scol;
  const ushort* pB = B + (size_t)(n0+srow)*K + scol;

  uint4 ra0 = *(const uint4*)(pA);  uint4 ra1 = *(const uint4*)(pA+8);
  uint4 rb0 = *(const uint4*)(pB);  uint4 rb1 = *(const uint4*)(pB+8);

  int sidx = srow*LDA + scol;
  for (int k0 = 0; k0 < K; k0 += 32){
    __syncthreads();
    *(uint4*)&Ah[sidx] = ra0; *(uint4*)&Ah[sidx+8] = ra1;
    *(uint4*)&Bh[sidx] = rb0; *(uint4*)&Bh[sidx+8] = rb1;
    __syncthreads();
    if (k0+32 < K){
      ra0 = *(const uint4*)(pA+k0+32); ra1 = *(const uint4*)(pA+k0+40);
      rb0 = *(const uint4*)(pB+k0+32); rb1 = *(const uint4*)(pB+k0+40);
    }
    bfrag af[4];
    #pragma unroll
    for (int mt=0; mt<4; mt++)
      af[mt] = *(const bfrag*)&Ah[(wm+mt*16+lm)*LDA + quad*8];
    #pragma unroll
    for (int nt=0; nt<4; nt++){
      bfrag bf = *(const bfrag*)&Bh[(wn+nt*16+lm)*LDA + quad*8];
      #pragma unroll
      for (int mt=0; mt<4; mt++)
        acc[mt][nt] = __builtin_amdgcn_mfma_f32_16x16x32_bf16(af[mt], bf, acc[mt][nt], 0,0,0);
    }
  }

  #pragma unroll
  for (int mt=0; mt<4; mt++){
    #pragma unroll
    for (int nt=0; nt<4; nt++){
      #pragma unroll
      for (int r=0;r<4;r++){
        int grow = m0 + wm + mt*16 + quad*4 + r;
        int gcol = n0 + wn + nt*16 + lm;
        size_t off = (size_t)grow*N + gcol;
        float v = acc[mt][nt][r];
        if (relu_res) v = fmaxf(v,0.f) + Res[off];
        if (Cf) Cf[off] = v;
        if (Cb) Cb[off] = f2bf(v);
      }
    }
  }
}

// ---------------- attention logits per (node,head) ----------------
__global__ __launch_bounds__(256) void compute_lg(const ushort* __restrict__ hbf,
    const float* __restrict__ a_src, const float* __restrict__ a_dst,
    float* __restrict__ lgs, float* __restrict__ lgd){
  int n = blockIdx.x; int t = threadIdx.x;
  int hd = t>>6, lane = t&63;
  uint4 g = *(const uint4*)(hbf + (size_t)n*FW + hd*HIDC + lane*8);
  float h[8] = {0,0,0,0,0,0,0,0};
  fma8(h, g, 1.0f);
  float4 as0 = *(const float4*)(a_src + hd*HIDC + lane*8);
  float4 as1 = *(const float4*)(a_src + hd*HIDC + lane*8 + 4);
  float4 ad0 = *(const float4*)(a_dst + hd*HIDC + lane*8);
  float4 ad1 = *(const float4*)(a_dst + hd*HIDC + lane*8 + 4);
  float s1 = h[0]*as0.x + h[1]*as0.y + h[2]*as0.z + h[3]*as0.w
           + h[4]*as1.x + h[5]*as1.y + h[6]*as1.z + h[7]*as1.w;
  float s2 = h[0]*ad0.x + h[1]*ad0.y + h[2]*ad0.z + h[3]*ad0.w
           + h[4]*ad1.x + h[5]*ad1.y + h[6]*ad1.z + h[7]*ad1.w;
  for (int off=32; off; off>>=1){ s1 += __shfl_down(s1,off); s2 += __shfl_down(s2,off); }
  if (lane==0){ lgs[n*HEADS+hd]=s1; lgd[n*HEADS+hd]=s2; }
}

// ---------------- CSR build helpers ----------------
__global__ __launch_bounds__(256) void hist_dst(const int* __restrict__ dst, int* __restrict__ indeg){
  int e = blockIdx.x*256+threadIdx.x; if (e<Ee) atomicAdd(&indeg[dst[e]],1);
}
__global__ __launch_bounds__(1024) void exscan(const int* __restrict__ cnt, int* __restrict__ rowptr, int n){
  __shared__ int sums[1024];
  int t = threadIdx.x;
  int v[4]; int s=0;
  #pragma unroll
  for (int i=0;i<4;i++){ int idx=t*4+i; v[i] = (idx<n)? cnt[idx] : 0; s+=v[i]; }
  sums[t]=s; __syncthreads();
  for (int off=1; off<1024; off<<=1){
    int other = (t>=off)? sums[t-off] : 0;
    __syncthreads();
    sums[t] += other;
    __syncthreads();
  }
  int run = (t>0)? sums[t-1] : 0;
  #pragma unroll
  for (int i=0;i<4;i++){ int idx=t*4+i; if (idx<n) rowptr[idx]=run; run+=v[i]; }
  if (t==1023) rowptr[n]=sums[1023];
}
__global__ __launch_bounds__(256) void scatter_dst(const int* __restrict__ src, const int* __restrict__ dst,
    const int* __restrict__ rowptr, int* __restrict__ fill, int* __restrict__ slist){
  int e = blockIdx.x*256+threadIdx.x; if (e>=Ee) return;
  int d = dst[e]; int p = atomicAdd(&fill[d],1); slist[rowptr[d]+p]=src[e];
}
__global__ __launch_bounds__(256) void dedup_mark(const int* __restrict__ src, const int* __restrict__ dst,
    unsigned int* __restrict__ bitmap, int* __restrict__ cnt, int* __restrict__ flag){
  int e = blockIdx.x*256+threadIdx.x; if (e>=Ee) return;
  unsigned int key = (unsigned int)src[e]*Nn + (unsigned int)dst[e];
  unsigned int bit = 1u<<(key&31);
  unsigned int old = atomicOr(&bitmap[key>>5], bit);
  if (!(old & bit)){ flag[e]=1; atomicAdd(&cnt[src[e]],1); }
}
__global__ __launch_bounds__(256) void scatter_src(const int* __restrict__ src, const int* __restrict__ dst,
    const int* __restrict__ flag, const int* __restrict__ rowptr, int* __restrict__ fill, int* __restrict__ cols){
  int e = blockIdx.x*256+threadIdx.x; if (e>=Ee) return;
  if (!flag[e]) return;
  int s = src[e]; int p = atomicAdd(&fill[s],1); cols[rowptr[s]+p] = dst[e];
}
__global__ __launch_bounds__(256) void compute_dinv(const int* __restrict__ cnt, float* __restrict__ dinv){
  int n = blockIdx.x*256+threadIdx.x; if (n<Nn) dinv[n] = 1.0f/sqrtf((float)(1+cnt[n]));
}

// ---------------- GAT softmax-aggregate: block = (4 nodes) x (1 head), wave = node ----------------
// head = blockIdx.x & 3  =>  XCD b%8 sees one 4MB head slice (L2 locality).
// Online softmax (single edge scan), chunk-0 logits kept in registers, 4x-batched gathers.
__global__ __launch_bounds__(256) void gat_aggregate(const ushort* __restrict__ hbf,
    const float* __restrict__ lgs, const float* __restrict__ lgd,
    const int* __restrict__ rowptr, const int* __restrict__ slist,
    float* __restrict__ Hfeat, ushort* __restrict__ Hbf){
  int t = threadIdx.x;
  int wv = __builtin_amdgcn_readfirstlane(t>>6);
  int lane = t&63;
  int b = blockIdx.x;
  int hd = __builtin_amdgcn_readfirstlane(b & 3);
  int n = ((b>>2)<<2) + wv;
  int beg = rowptr[n], deg = rowptr[n+1]-beg;
  float ldst = lgd[n*HEADS+hd];
  // ---- single-pass online softmax (m,z) ----
  float m_ = -3.4e38f, z_ = 0.f;
  int   s0 = 0; float v0 = 0.f;          // chunk-0 edge cached per lane
  for (int i=lane; i<deg; i+=64){
    int s = slist[beg+i];
    float v = lgs[s*HEADS+hd] + ldst;
    v = v>0.f ? v : 0.2f*v;
    if (i<64){ s0=s; v0=v; }
    float mn = fmaxf(m_, v);
    z_ = z_*__expf(m_-mn) + __expf(v-mn);
    m_ = mn;
  }
  for (int o=32;o;o>>=1){
    float mo = __shfl_down(m_,o), zo = __shfl_down(z_,o);
    float mn = fmaxf(m_, mo);
    z_ = z_*__expf(m_-mn) + zo*__expf(mo-mn);
    m_ = mn;
  }
  float mx = __shfl(m_,0);
  float zs = __shfl(z_,0);
  float inv = 1.f/(zs+1e-16f);
  // ---- weighted accumulate, 64-edge chunks, 4x-batched loads ----
  float acc[8] = {0,0,0,0,0,0,0,0};
  const ushort* hb = hbf + hd*HIDC + lane*8;
  for (int base=0; base<deg; base+=64){
    float al; int s;
    if (base==0){
      s = s0;
      al = (lane<deg) ? __expf(v0-mx)*inv : 0.f;
    } else {
      int i = base+lane;
      al = 0.f; s = 0;
      if (i<deg){
        s = slist[beg+i];
        float v = lgs[s*HEADS+hd] + ldst; v = v>0.f ? v : 0.2f*v;
        al = __expf(v-mx)*inv;
      }
    }
    int cn = min(64, deg-base);
    int c = 0;
    for (; c+4<=cn; c+=4){
      float a0=__shfl(al,c),   a1=__shfl(al,c+1), a2=__shfl(al,c+2), a3=__shfl(al,c+3);
      int   s0_=__shfl(s,c),   s1_=__shfl(s,c+1), s2_=__shfl(s,c+2), s3_=__shfl(s,c+3);
      uint4 g0 = *(const uint4*)(hb + (size_t)s0_*FW);
      uint4 g1 = *(const uint4*)(hb + (size_t)s1_*FW);
      uint4 g2 = *(const uint4*)(hb + (size_t)s2_*FW);
      uint4 g3 = *(const uint4*)(hb + (size_t)s3_*FW);
      fma8(acc, g0, a0); fma8(acc, g1, a1); fma8(acc, g2, a2); fma8(acc, g3, a3);
    }
    for (; c<cn; c++){
      float a = __shfl(al,c);
      int ss  = __shfl(s,c);
      uint4 g = *(const uint4*)(hb + (size_t)ss*FW);
      fma8(acc, g, a);
    }
  }
  size_t off = (size_t)n*FW + hd*HIDC + lane*8;
  *(float4*)(Hfeat + off)     = make_float4(acc[0],acc[1],acc[2],acc[3]);
  *(float4*)(Hfeat + off + 4) = make_float4(acc[4],acc[5],acc[6],acc[7]);
  *(uint4*)(Hbf + off) = pack8(acc);
}

// ---------------- SpMM: block = (4 nodes) x (1 chunk), chunk = blockIdx.x & 3 ----------------
// 4x-batched gathers for load ILP.
__global__ __launch_bounds__(256) void spmm_bf(const ushort* __restrict__ Hbf,
    ushort* __restrict__ Phi,
    const int* __restrict__ rowptr, const int* __restrict__ cols, const float* __restrict__ dinv){
  int t = threadIdx.x;
  int wv = __builtin_amdgcn_readfirstlane(t>>6);
  int lane = t&63;
  int b = blockIdx.x;
  int ck = __builtin_amdgcn_readfirstlane(b & 3);
  int n = ((b>>2)<<2) + wv;
  int f = (ck<<9) + lane*8;
  float di = dinv[n];
  float acc[8] = {0,0,0,0,0,0,0,0};
  const ushort* hb = Hbf + f;
  uint4 self = *(const uint4*)(hb + (size_t)n*FW);
  fma8(acc, self, di*di);
  int beg = rowptr[n], end = rowptr[n+1];
  for (int base=beg; base<end; base+=64){
    int i = base + lane;
    int m = n; float w = 0.f;
    if (i < end){ m = cols[i]; w = di*dinv[m]; }
    int cn = min(64, end-base);
    int c = 0;
    for (; c+4<=cn; c+=4){
      int   m0=__shfl(m,c),   m1=__shfl(m,c+1), m2=__shfl(m,c+2), m3=__shfl(m,c+3);
      float w0=__shfl(w,c),   w1=__shfl(w,c+1), w2=__shfl(w,c+2), w3=__shfl(w,c+3);
      uint4 g0 = *(const uint4*)(hb + (size_t)m0*FW);
      uint4 g1 = *(const uint4*)(hb + (size_t)m1*FW);
      uint4 g2 = *(const uint4*)(hb + (size_t)m2*FW);
      uint4 g3 = *(const uint4*)(hb + (size_t)m3*FW);
      fma8(acc, g0, w0); fma8(acc, g1, w1); fma8(acc, g2, w2); fma8(acc, g3, w3);
    }
    for (; c<cn; c++){
      int mm   = __shfl(m,c);
      float ww = __shfl(w,c);
      uint4 g = *(const uint4*)(hb + (size_t)mm*FW);
      fma8(acc, g, ww);
    }
  }
  *(uint4*)(Phi + (size_t)n*FW + f) = pack8(acc);
}

// ---------------- pooling ----------------
__global__ __launch_bounds__(256) void graph_offsets(const int* __restrict__ batch, int* __restrict__ goff){
  __shared__ int cnt[GG];
  int t = threadIdx.x;
  if (t<GG) cnt[t]=0;
  __syncthreads();
  for (int i=t;i<Nn;i+=256) atomicAdd(&cnt[batch[i]],1);
  __syncthreads();
  if (t==0){ int run=0; for (int g=0; g<GG; g++){ goff[g]=run; run+=cnt[g]; } goff[GG]=run; }
}
// segmented sum into psum[G][FW] via atomics; batch is sorted
__global__ __launch_bounds__(256) void pool_accum(const float* __restrict__ H,
    const int* __restrict__ batch, float* __restrict__ psum){
  int d = blockIdx.y*256 + threadIdx.x;
  int n0 = blockIdx.x*32;
  int g = batch[n0];
  float s = 0.f;
  for (int k=0;k<32;k++){
    int n = n0+k;
    int gn = batch[n];
    if (gn != g){ atomicAdd(&psum[(size_t)g*FW+d], s); s=0.f; g=gn; }
    s += H[(size_t)n*FW + d];
  }
  atomicAdd(&psum[(size_t)g*FW+d], s);
}
__global__ __launch_bounds__(256) void final_out(const float* __restrict__ psum,
    const int* __restrict__ goff,
    const float* __restrict__ fc_w, const float* __restrict__ fc_b, float* __restrict__ out){
  int g = blockIdx.x; int t = threadIdx.x;
  float cinv = 0.25f / fmaxf((float)(goff[g+1]-goff[g]), 1.f);
  float p = 0.f;
  for (int d=t; d<HIDC; d+=256){
    float f = cinv*(psum[(size_t)g*FW+d] + psum[(size_t)g*FW+HIDC+d]
                  + psum[(size_t)g*FW+2*HIDC+d] + psum[(size_t)g*FW+3*HIDC+d]);
    p += f*fc_w[d];
  }
  __shared__ float red[4];
  for (int off=32; off; off>>=1) p += __shfl_down(p,off);
  if ((t&63)==0) red[t>>6]=p;
  __syncthreads();
  if (t==0) out[g] = red[0]+red[1]+red[2]+red[3] + fc_b[0];
}

extern "C" void kernel_launch(void* const* d_in, const int* in_sizes, int n_in,
                              void* d_out, int out_size, void* d_ws, size_t ws_size,
                              hipStream_t stream){
  const float* x      = (const float*)d_in[0];
  const int*   ei     = (const int*)d_in[1];
  const int*   batch  = (const int*)d_in[2];
  const float* W_gat  = (const float*)d_in[3];
  const float* a_src  = (const float*)d_in[4];
  const float* a_dst  = (const float*)d_in[5];
  const float* W_gcn  = (const float*)d_in[6];
  const float* fc_w   = (const float*)d_in[7];
  const float* fc_b   = (const float*)d_in[8];
  float* out = (float*)d_out;
  const int* src = ei;
  const int* dst = ei + Ee;

  char* w = (char*)d_ws;
  size_t off = 0;
  auto alloc = [&](size_t bytes)->char*{ char* p = w + off; off = (off + bytes + 255) & ~(size_t)255; return p; };
  float*  Hfeat  = (float*)alloc((size_t)Nn*FW*4);
  ushort* hbf    = (ushort*)alloc((size_t)Nn*FW*2);       // GAT projection; REUSED as Phi
  ushort* Hbf    = (ushort*)alloc((size_t)Nn*FW*2);
  ushort* Xbf    = (ushort*)alloc((size_t)Nn*INC*2);
  ushort* WgatT  = (ushort*)alloc((size_t)HEADS*INC*HIDC*2);
  ushort* WgcnT  = (ushort*)alloc((size_t)NLAY*HIDC*HIDC*2);
  float* lgs    = (float*)alloc((size_t)Nn*HEADS*4);
  float* lgd    = (float*)alloc((size_t)Nn*HEADS*4);
  int* indeg    = (int*)alloc(Nn*4);
  int* rowptr_d = (int*)alloc((Nn+1)*4);
  int* slist    = (int*)alloc(Ee*4);
  int* fill_d   = (int*)alloc(Nn*4);
  unsigned int* bitmap = (unsigned int*)alloc((size_t)Nn*Nn/8);
  int* cnt_s    = (int*)alloc(Nn*4);
  int* rowptr_s = (int*)alloc((Nn+1)*4);
  int* cols     = (int*)alloc(Ee*4);
  int* fill_s   = (int*)alloc(Nn*4);
  int* flag     = (int*)alloc(Ee*4);
  float* dinv   = (float*)alloc(Nn*4);
  float* psum   = (float*)alloc((size_t)GG*FW*4);
  int* goff     = (int*)alloc((GG+1)*4);
  ushort* Phi   = hbf;

  hipMemsetAsync(indeg, 0, Nn*4, stream);
  hipMemsetAsync(fill_d, 0, Nn*4, stream);
  hipMemsetAsync(cnt_s, 0, Nn*4, stream);
  hipMemsetAsync(fill_s, 0, Nn*4, stream);
  hipMemsetAsync(flag, 0, Ee*4, stream);
  hipMemsetAsync(bitmap, 0, (size_t)Nn*Nn/8, stream);
  hipMemsetAsync(psum, 0, (size_t)GG*FW*4, stream);

  // ---- input prep ----
  tobf<<<(Nn*INC)/256,256,0,stream>>>(x, Xbf);
  tbf<<<dim3(16,16,HEADS),256,0,stream>>>(W_gat, WgatT);
  tbf<<<dim3(16,16,NLAY),256,0,stream>>>(W_gcn, WgcnT);

  // ---- GAT projection (bf16 MFMA) ----
  gemm_bf<<<dim3(FW/128, Nn/128),256,0,stream>>>(Xbf, WgatT,
      nullptr, nullptr, hbf, Nn, FW, INC, 0);
  compute_lg<<<Nn,256,0,stream>>>(hbf, a_src, a_dst, lgs, lgd);

  // ---- CSR by dst for attention ----
  hist_dst<<<Ee/256,256,0,stream>>>(dst, indeg);
  exscan<<<1,1024,0,stream>>>(indeg, rowptr_d, Nn);
  scatter_dst<<<Ee/256,256,0,stream>>>(src, dst, rowptr_d, fill_d, slist);
  gat_aggregate<<<Nn,256,0,stream>>>(hbf, lgs, lgd, rowptr_d, slist, Hfeat, Hbf);

  // ---- dedup'd adjacency (set-semantics) + GCN normalization ----
  dedup_mark<<<Ee/256,256,0,stream>>>(src, dst, bitmap, cnt_s, flag);
  exscan<<<1,1024,0,stream>>>(cnt_s, rowptr_s, Nn);
  scatter_src<<<Ee/256,256,0,stream>>>(src, dst, flag, rowptr_s, fill_s, cols);
  compute_dinv<<<Nn/256,256,0,stream>>>(cnt_s, dinv);

  // ---- residual GCN layers ----
  for (int l=0;l<NLAY;l++){
    spmm_bf<<<Nn,256,0,stream>>>(Hbf, Phi, rowptr_s, cols, dinv);
    gemm_bf<<<dim3(HIDC/128, (Nn*HEADS)/128),256,0,stream>>>(Phi,
        WgcnT + (size_t)l*HIDC*HIDC,
        Hfeat, Hfeat, (l==NLAY-1)? nullptr : Hbf, Nn*HEADS, HIDC, HIDC, 1);
  }

  // ---- pooling + FC ----
  graph_offsets<<<1,256,0,stream>>>(batch, goff);
  pool_accum<<<dim3(Nn/32, FW/256),256,0,stream>>>(Hfeat, batch, psum);
  final_out<<<GG,256,0,stream>>>(psum, goff, fc_w, fc_b, out);
}

// Round 6
// 407.627 us; speedup vs baseline: 2.9992x; 1.0422x over previous
//
#include <hip/hip_runtime.h>
#include <cstdint>
#include <cstddef>

#define Nn    4096
#define Ee    131072
#define INC   512
#define HIDC  512
#define HEADS 4
#define NLAY  3
#define GG    16
#define FW    2048   // HEADS*HIDC

typedef __attribute__((ext_vector_type(8))) short bfrag;   // 8 bf16 (4 VGPRs)
typedef __attribute__((ext_vector_type(4))) float ffrag;   // 4 fp32 acc

__device__ __forceinline__ ushort f2bf(float v){
  uint u = __builtin_bit_cast(uint, v);
  u += 0x7fffu + ((u>>16)&1u);          // RNE
  return (ushort)(u>>16);
}
__device__ __forceinline__ float bf2f(ushort s){
  uint u = ((uint)s)<<16; return __builtin_bit_cast(float, u);
}
// acc[0..7] += w * unpack8(bf16x8 in uint4)  (feature order: low16 first)
__device__ __forceinline__ void fma8(float* acc, uint4 g, float w){
  uint u[4] = {g.x, g.y, g.z, g.w};
  #pragma unroll
  for (int q=0;q<4;q++){
    float lo = __builtin_bit_cast(float, u[q]<<16);
    float hi = __builtin_bit_cast(float, u[q] & 0xffff0000u);
    acc[2*q]   += w*lo;
    acc[2*q+1] += w*hi;
  }
}
__device__ __forceinline__ uint4 pack8(const float* a){
  uint4 o;
  o.x = (uint)f2bf(a[0]) | ((uint)f2bf(a[1])<<16);
  o.y = (uint)f2bf(a[2]) | ((uint)f2bf(a[3])<<16);
  o.z = (uint)f2bf(a[4]) | ((uint)f2bf(a[5])<<16);
  o.w = (uint)f2bf(a[6]) | ((uint)f2bf(a[7])<<16);
  return o;
}

// ---------------- fp32 -> bf16 elementwise ----------------
__global__ __launch_bounds__(256) void tobf(const float* __restrict__ X, ushort* __restrict__ Xb){
  int i = blockIdx.x*256 + threadIdx.x;
  Xb[i] = f2bf(X[i]);
}

// ---------------- batched 512x512 transpose -> bf16: W[b][r][c] -> T[b][c][r] ----------------
__global__ __launch_bounds__(256) void tbf(const float* __restrict__ W, ushort* __restrict__ T){
  __shared__ float tile[32][33];
  int b = blockIdx.z;
  int r0 = blockIdx.y*32, c0 = blockIdx.x*32;
  int t = threadIdx.x;
  int i = t>>3, j0 = (t&7)*4;
  const float* Wb = W + (size_t)b*512*512;
  float4 v = *(const float4*)(Wb + (size_t)(r0+i)*512 + c0 + j0);
  tile[i][j0]=v.x; tile[i][j0+1]=v.y; tile[i][j0+2]=v.z; tile[i][j0+3]=v.w;
  __syncthreads();
  ushort* o = T + (size_t)b*512*512 + (size_t)(c0+i)*512 + r0 + j0;
  #pragma unroll
  for (int q=0;q<4;q++) o[q] = f2bf(tile[j0+q][i]);
}

// ---------------- bf16 MFMA GEMM: C = A@B^T, 128x128 tile ----------------
// LDS tiles in fragment-major layout [kquad][row][8 shorts]:
//   offset(row,k) = ((k>>3)*128 + row)*8 + (k&7)
// => every ds_read_b128 hits the canonical lane*16B pattern (zero excess conflicts).
__global__ __launch_bounds__(256) void gemm_bf(
    const ushort* __restrict__ A, const ushort* __restrict__ B,
    const float* __restrict__ Res, float* __restrict__ Cf, ushort* __restrict__ Cb,
    int M, int N, int K, int relu_res)
{
  __shared__ __align__(16) ushort Ah[4096];   // 128 rows x 32 k = 8 KB
  __shared__ __align__(16) ushort Bh[4096];
  int t = threadIdx.x;
  int m0 = blockIdx.y*128, n0 = blockIdx.x*128;
  int srow = t>>1, c = t&1, scol = c*16;       // stage: 2 threads/row, 16 shorts each
  int wave = t>>6, lane = t&63;
  int wm = (wave&1)*64, wn = (wave>>1)*64;
  int lm = lane&15, quad = lane>>4;

  ffrag acc[4][4];
  #pragma unroll
  for (int i=0;i<4;i++){
    #pragma unroll
    for (int j=0;j<4;j++) acc[i][j] = (ffrag){0.f,0.f,0.f,0.f};
  }

  const ushort* pA = A + (size_t)(m0+srow)*K + scol;
  const ushort* pB = B + (size_t)(n0+srow)*K + scol;

  uint4 ra0 = *(const uint4*)(pA);  uint4 ra1 = *(const uint4*)(pA+8);
  uint4 rb0 = *(const uint4*)(pB);  uint4 rb1 = *(const uint4*)(pB+8);

  int w0 = ((2*c)*128 + srow)*8;     // quad 2c  (shorts scol..scol+7)
  int w1 = w0 + 1024;                // quad 2c+1 (shorts scol+8..scol+15)
  for (int k0 = 0; k0 < K; k0 += 32){
    __syncthreads();
    *(uint4*)&Ah[w0] = ra0; *(uint4*)&Ah[w1] = ra1;
    *(uint4*)&Bh[w0] = rb0; *(uint4*)&Bh[w1] = rb1;
    __syncthreads();
    if (k0+32 < K){
      ra0 = *(const uint4*)(pA+k0+32); ra1 = *(const uint4*)(pA+k0+40);
      rb0 = *(const uint4*)(pB+k0+32); rb1 = *(const uint4*)(pB+k0+40);
    }
    bfrag af[4];
    #pragma unroll
    for (int mt=0; mt<4; mt++)
      af[mt] = *(const bfrag*)&Ah[(quad*128 + wm + mt*16 + lm)*8];
    #pragma unroll
    for (int nt=0; nt<4; nt++){
      bfrag bf = *(const bfrag*)&Bh[(quad*128 + wn + nt*16 + lm)*8];
      #pragma unroll
      for (int mt=0; mt<4; mt++)
        acc[mt][nt] = __builtin_amdgcn_mfma_f32_16x16x32_bf16(af[mt], bf, acc[mt][nt], 0,0,0);
    }
  }

  #pragma unroll
  for (int mt=0; mt<4; mt++){
    #pragma unroll
    for (int nt=0; nt<4; nt++){
      #pragma unroll
      for (int r=0;r<4;r++){
        int grow = m0 + wm + mt*16 + quad*4 + r;
        int gcol = n0 + wn + nt*16 + lm;
        size_t off = (size_t)grow*N + gcol;
        float v = acc[mt][nt][r];
        if (relu_res) v = fmaxf(v,0.f) + Res[off];
        if (Cf) Cf[off] = v;
        if (Cb) Cb[off] = f2bf(v);
      }
    }
  }
}

// ---------------- attention logits per (node,head) ----------------
__global__ __launch_bounds__(256) void compute_lg(const ushort* __restrict__ hbf,
    const float* __restrict__ a_src, const float* __restrict__ a_dst,
    float* __restrict__ lgs, float* __restrict__ lgd){
  int n = blockIdx.x; int t = threadIdx.x;
  int hd = t>>6, lane = t&63;
  uint4 g = *(const uint4*)(hbf + (size_t)n*FW + hd*HIDC + lane*8);
  float h[8] = {0,0,0,0,0,0,0,0};
  fma8(h, g, 1.0f);
  float4 as0 = *(const float4*)(a_src + hd*HIDC + lane*8);
  float4 as1 = *(const float4*)(a_src + hd*HIDC + lane*8 + 4);
  float4 ad0 = *(const float4*)(a_dst + hd*HIDC + lane*8);
  float4 ad1 = *(const float4*)(a_dst + hd*HIDC + lane*8 + 4);
  float s1 = h[0]*as0.x + h[1]*as0.y + h[2]*as0.z + h[3]*as0.w
           + h[4]*as1.x + h[5]*as1.y + h[6]*as1.z + h[7]*as1.w;
  float s2 = h[0]*ad0.x + h[1]*ad0.y + h[2]*ad0.z + h[3]*ad0.w
           + h[4]*ad1.x + h[5]*ad1.y + h[6]*ad1.z + h[7]*ad1.w;
  for (int off=32; off; off>>=1){ s1 += __shfl_down(s1,off); s2 += __shfl_down(s2,off); }
  if (lane==0){ lgs[n*HEADS+hd]=s1; lgd[n*HEADS+hd]=s2; }
}

// ---------------- fused edge pass 1: in-degree hist + set-semantics dedup ----------------
__global__ __launch_bounds__(256) void edge_pass1(const int* __restrict__ src, const int* __restrict__ dst,
    int* __restrict__ indeg, unsigned int* __restrict__ bitmap,
    int* __restrict__ cnt_s, int* __restrict__ flag){
  int e = blockIdx.x*256+threadIdx.x; if (e>=Ee) return;
  int s = src[e], d = dst[e];
  atomicAdd(&indeg[d],1);
  unsigned int key = (unsigned int)s*Nn + (unsigned int)d;
  unsigned int bit = 1u<<(key&31);
  unsigned int old = atomicOr(&bitmap[key>>5], bit);
  int f = (old & bit) ? 0 : 1;
  flag[e] = f;
  if (f) atomicAdd(&cnt_s[s],1);
}

// ---------------- dual exclusive scan: block 0 -> rowptr_d, block 1 -> rowptr_s ----------------
__global__ __launch_bounds__(1024) void exscan2(const int* __restrict__ cnt0, int* __restrict__ rp0,
    const int* __restrict__ cnt1, int* __restrict__ rp1){
  const int* cnt = blockIdx.x ? cnt1 : cnt0;
  int* rowptr    = blockIdx.x ? rp1  : rp0;
  __shared__ int sums[1024];
  int t = threadIdx.x;
  int v[4]; int s=0;
  #pragma unroll
  for (int i=0;i<4;i++){ int idx=t*4+i; v[i] = cnt[idx]; s+=v[i]; }
  sums[t]=s; __syncthreads();
  for (int off=1; off<1024; off<<=1){
    int other = (t>=off)? sums[t-off] : 0;
    __syncthreads();
    sums[t] += other;
    __syncthreads();
  }
  int run = (t>0)? sums[t-1] : 0;
  #pragma unroll
  for (int i=0;i<4;i++){ int idx=t*4+i; rowptr[idx]=run; run+=v[i]; }
  if (t==1023) rowptr[Nn]=sums[1023];
}

__global__ __launch_bounds__(256) void compute_dinv(const int* __restrict__ cnt, float* __restrict__ dinv){
  int n = blockIdx.x*256+threadIdx.x; if (n<Nn) dinv[n] = 1.0f/sqrtf((float)(1+cnt[n]));
}

// ---------------- fused edge pass 2: scatter dst-CSR (src vals) + src-CSR (col,dinv) ----------------
__global__ __launch_bounds__(256) void edge_pass2(const int* __restrict__ src, const int* __restrict__ dst,
    const int* __restrict__ flag,
    const int* __restrict__ rp_d, int* __restrict__ fill_d, int* __restrict__ slist,
    const int* __restrict__ rp_s, int* __restrict__ fill_s, int2* __restrict__ cw,
    const float* __restrict__ dinv){
  int e = blockIdx.x*256+threadIdx.x; if (e>=Ee) return;
  int s = src[e], d = dst[e];
  int p = atomicAdd(&fill_d[d],1); slist[rp_d[d]+p] = s;
  if (flag[e]){
    int q = atomicAdd(&fill_s[s],1);
    cw[rp_s[s]+q] = make_int2(d, __float_as_int(dinv[d]));
  }
}

// ---------------- GAT softmax-aggregate: block = (4 nodes) x (1 head), wave = node ----------------
// head = blockIdx.x & 3  =>  XCD b%8 sees one 4MB head slice (L2 locality).
// Online softmax (single edge scan), chunk-0 logits kept in registers, 4x-batched gathers.
__global__ __launch_bounds__(256) void gat_aggregate(const ushort* __restrict__ hbf,
    const float* __restrict__ lgs, const float* __restrict__ lgd,
    const int* __restrict__ rowptr, const int* __restrict__ slist,
    float* __restrict__ Hfeat, ushort* __restrict__ Hbf){
  int t = threadIdx.x;
  int wv = __builtin_amdgcn_readfirstlane(t>>6);
  int lane = t&63;
  int b = blockIdx.x;
  int hd = __builtin_amdgcn_readfirstlane(b & 3);
  int n = ((b>>2)<<2) + wv;
  int beg = rowptr[n], deg = rowptr[n+1]-beg;
  float ldst = lgd[n*HEADS+hd];
  // ---- single-pass online softmax (m,z) ----
  float m_ = -3.4e38f, z_ = 0.f;
  int   s0 = 0; float v0 = 0.f;          // chunk-0 edge cached per lane
  for (int i=lane; i<deg; i+=64){
    int s = slist[beg+i];
    float v = lgs[s*HEADS+hd] + ldst;
    v = v>0.f ? v : 0.2f*v;
    if (i<64){ s0=s; v0=v; }
    float mn = fmaxf(m_, v);
    z_ = z_*__expf(m_-mn) + __expf(v-mn);
    m_ = mn;
  }
  for (int o=32;o;o>>=1){
    float mo = __shfl_down(m_,o), zo = __shfl_down(z_,o);
    float mn = fmaxf(m_, mo);
    z_ = z_*__expf(m_-mn) + zo*__expf(mo-mn);
    m_ = mn;
  }
  float mx = __shfl(m_,0);
  float zs = __shfl(z_,0);
  float inv = 1.f/(zs+1e-16f);
  // ---- weighted accumulate, 64-edge chunks, 4x-batched loads ----
  float acc[8] = {0,0,0,0,0,0,0,0};
  const ushort* hb = hbf + hd*HIDC + lane*8;
  for (int base=0; base<deg; base+=64){
    float al; int s;
    if (base==0){
      s = s0;
      al = (lane<deg) ? __expf(v0-mx)*inv : 0.f;
    } else {
      int i = base+lane;
      al = 0.f; s = 0;
      if (i<deg){
        s = slist[beg+i];
        float v = lgs[s*HEADS+hd] + ldst; v = v>0.f ? v : 0.2f*v;
        al = __expf(v-mx)*inv;
      }
    }
    int cn = min(64, deg-base);
    int c = 0;
    for (; c+4<=cn; c+=4){
      float a0=__shfl(al,c),   a1=__shfl(al,c+1), a2=__shfl(al,c+2), a3=__shfl(al,c+3);
      int   s0_=__shfl(s,c),   s1_=__shfl(s,c+1), s2_=__shfl(s,c+2), s3_=__shfl(s,c+3);
      uint4 g0 = *(const uint4*)(hb + (size_t)s0_*FW);
      uint4 g1 = *(const uint4*)(hb + (size_t)s1_*FW);
      uint4 g2 = *(const uint4*)(hb + (size_t)s2_*FW);
      uint4 g3 = *(const uint4*)(hb + (size_t)s3_*FW);
      fma8(acc, g0, a0); fma8(acc, g1, a1); fma8(acc, g2, a2); fma8(acc, g3, a3);
    }
    for (; c<cn; c++){
      float a = __shfl(al,c);
      int ss  = __shfl(s,c);
      uint4 g = *(const uint4*)(hb + (size_t)ss*FW);
      fma8(acc, g, a);
    }
  }
  size_t off = (size_t)n*FW + hd*HIDC + lane*8;
  *(float4*)(Hfeat + off)     = make_float4(acc[0],acc[1],acc[2],acc[3]);
  *(float4*)(Hfeat + off + 4) = make_float4(acc[4],acc[5],acc[6],acc[7]);
  *(uint4*)(Hbf + off) = pack8(acc);
}

// ---------------- SpMM: block = (4 nodes) x (1 chunk), chunk = blockIdx.x & 3 ----------------
// packed (col, dinv[col]) pairs -> one 8B load per edge; 4x-batched gathers.
__global__ __launch_bounds__(256) void spmm_bf(const ushort* __restrict__ Hbf,
    ushort* __restrict__ Phi,
    const int* __restrict__ rowptr, const int2* __restrict__ cw, const float* __restrict__ dinv){
  int t = threadIdx.x;
  int wv = __builtin_amdgcn_readfirstlane(t>>6);
  int lane = t&63;
  int b = blockIdx.x;
  int ck = __builtin_amdgcn_readfirstlane(b & 3);
  int n = ((b>>2)<<2) + wv;
  int f = (ck<<9) + lane*8;
  float di = dinv[n];
  float acc[8] = {0,0,0,0,0,0,0,0};
  const ushort* hb = Hbf + f;
  uint4 self = *(const uint4*)(hb + (size_t)n*FW);
  fma8(acc, self, di*di);
  int beg = rowptr[n], end = rowptr[n+1];
  for (int base=beg; base<end; base+=64){
    int i = base + lane;
    int m = n; float w = 0.f;
    if (i < end){ int2 e = cw[i]; m = e.x; w = di*__int_as_float(e.y); }
    int cn = min(64, end-base);
    int c = 0;
    for (; c+4<=cn; c+=4){
      int   m0=__shfl(m,c),   m1=__shfl(m,c+1), m2=__shfl(m,c+2), m3=__shfl(m,c+3);
      float w0=__shfl(w,c),   w1=__shfl(w,c+1), w2=__shfl(w,c+2), w3=__shfl(w,c+3);
      uint4 g0 = *(const uint4*)(hb + (size_t)m0*FW);
      uint4 g1 = *(const uint4*)(hb + (size_t)m1*FW);
      uint4 g2 = *(const uint4*)(hb + (size_t)m2*FW);
      uint4 g3 = *(const uint4*)(hb + (size_t)m3*FW);
      fma8(acc, g0, w0); fma8(acc, g1, w1); fma8(acc, g2, w2); fma8(acc, g3, w3);
    }
    for (; c<cn; c++){
      int mm   = __shfl(m,c);
      float ww = __shfl(w,c);
      uint4 g = *(const uint4*)(hb + (size_t)mm*FW);
      fma8(acc, g, ww);
    }
  }
  *(uint4*)(Phi + (size_t)n*FW + f) = pack8(acc);
}

// ---------------- pooling ----------------
__global__ __launch_bounds__(256) void graph_offsets(const int* __restrict__ batch, int* __restrict__ goff){
  __shared__ int cnt[GG];
  int t = threadIdx.x;
  if (t<GG) cnt[t]=0;
  __syncthreads();
  for (int i=t;i<Nn;i+=256) atomicAdd(&cnt[batch[i]],1);
  __syncthreads();
  if (t==0){ int run=0; for (int g=0; g<GG; g++){ goff[g]=run; run+=cnt[g]; } goff[GG]=run; }
}
// segmented sum into psum[G][FW] via atomics; batch is sorted
__global__ __launch_bounds__(256) void pool_accum(const float* __restrict__ H,
    const int* __restrict__ batch, float* __restrict__ psum){
  int d = blockIdx.y*256 + threadIdx.x;
  int n0 = blockIdx.x*32;
  int g = batch[n0];
  float s = 0.f;
  for (int k=0;k<32;k++){
    int n = n0+k;
    int gn = batch[n];
    if (gn != g){ atomicAdd(&psum[(size_t)g*FW+d], s); s=0.f; g=gn; }
    s += H[(size_t)n*FW + d];
  }
  atomicAdd(&psum[(size_t)g*FW+d], s);
}
__global__ __launch_bounds__(256) void final_out(const float* __restrict__ psum,
    const int* __restrict__ goff,
    const float* __restrict__ fc_w, const float* __restrict__ fc_b, float* __restrict__ out){
  int g = blockIdx.x; int t = threadIdx.x;
  float cinv = 0.25f / fmaxf((float)(goff[g+1]-goff[g]), 1.f);
  float p = 0.f;
  for (int d=t; d<HIDC; d+=256){
    float f = cinv*(psum[(size_t)g*FW+d] + psum[(size_t)g*FW+HIDC+d]
                  + psum[(size_t)g*FW+2*HIDC+d] + psum[(size_t)g*FW+3*HIDC+d]);
    p += f*fc_w[d];
  }
  __shared__ float red[4];
  for (int off=32; off; off>>=1) p += __shfl_down(p,off);
  if ((t&63)==0) red[t>>6]=p;
  __syncthreads();
  if (t==0) out[g] = red[0]+red[1]+red[2]+red[3] + fc_b[0];
}

extern "C" void kernel_launch(void* const* d_in, const int* in_sizes, int n_in,
                              void* d_out, int out_size, void* d_ws, size_t ws_size,
                              hipStream_t stream){
  const float* x      = (const float*)d_in[0];
  const int*   ei     = (const int*)d_in[1];
  const int*   batch  = (const int*)d_in[2];
  const float* W_gat  = (const float*)d_in[3];
  const float* a_src  = (const float*)d_in[4];
  const float* a_dst  = (const float*)d_in[5];
  const float* W_gcn  = (const float*)d_in[6];
  const float* fc_w   = (const float*)d_in[7];
  const float* fc_b   = (const float*)d_in[8];
  float* out = (float*)d_out;
  const int* src = ei;
  const int* dst = ei + Ee;

  char* w = (char*)d_ws;
  size_t off = 0;
  auto alloc = [&](size_t bytes)->char*{ char* p = w + off; off = (off + bytes + 255) & ~(size_t)255; return p; };
  float*  Hfeat  = (float*)alloc((size_t)Nn*FW*4);
  ushort* hbf    = (ushort*)alloc((size_t)Nn*FW*2);       // GAT projection; REUSED as Phi
  ushort* Hbf    = (ushort*)alloc((size_t)Nn*FW*2);
  ushort* Xbf    = (ushort*)alloc((size_t)Nn*INC*2);
  ushort* WgatT  = (ushort*)alloc((size_t)HEADS*INC*HIDC*2);
  ushort* WgcnT  = (ushort*)alloc((size_t)NLAY*HIDC*HIDC*2);
  float* lgs    = (float*)alloc((size_t)Nn*HEADS*4);
  float* lgd    = (float*)alloc((size_t)Nn*HEADS*4);
  int* indeg    = (int*)alloc(Nn*4);
  int* rowptr_d = (int*)alloc((Nn+1)*4);
  int* slist    = (int*)alloc(Ee*4);
  int* fill_d   = (int*)alloc(Nn*4);
  unsigned int* bitmap = (unsigned int*)alloc((size_t)Nn*Nn/8);
  int* cnt_s    = (int*)alloc(Nn*4);
  int* rowptr_s = (int*)alloc((Nn+1)*4);
  int2* cwlist  = (int2*)alloc((size_t)Ee*8);
  int* fill_s   = (int*)alloc(Nn*4);
  int* flag     = (int*)alloc(Ee*4);
  float* dinv   = (float*)alloc(Nn*4);
  float* psum   = (float*)alloc((size_t)GG*FW*4);
  int* goff     = (int*)alloc((GG+1)*4);
  ushort* Phi   = hbf;

  hipMemsetAsync(indeg, 0, Nn*4, stream);
  hipMemsetAsync(fill_d, 0, Nn*4, stream);
  hipMemsetAsync(cnt_s, 0, Nn*4, stream);
  hipMemsetAsync(fill_s, 0, Nn*4, stream);
  hipMemsetAsync(bitmap, 0, (size_t)Nn*Nn/8, stream);
  hipMemsetAsync(psum, 0, (size_t)GG*FW*4, stream);

  // ---- input prep ----
  tobf<<<(Nn*INC)/256,256,0,stream>>>(x, Xbf);
  tbf<<<dim3(16,16,HEADS),256,0,stream>>>(W_gat, WgatT);
  tbf<<<dim3(16,16,NLAY),256,0,stream>>>(W_gcn, WgcnT);

  // ---- GAT projection (bf16 MFMA) ----
  gemm_bf<<<dim3(FW/128, Nn/128),256,0,stream>>>(Xbf, WgatT,
      nullptr, nullptr, hbf, Nn, FW, INC, 0);
  compute_lg<<<Nn,256,0,stream>>>(hbf, a_src, a_dst, lgs, lgd);

  // ---- fused CSR build (dst-CSR for attention; dedup'd src-CSR + GCN norm) ----
  edge_pass1<<<Ee/256,256,0,stream>>>(src, dst, indeg, bitmap, cnt_s, flag);
  exscan2<<<2,1024,0,stream>>>(indeg, rowptr_d, cnt_s, rowptr_s);
  compute_dinv<<<Nn/256,256,0,stream>>>(cnt_s, dinv);
  edge_pass2<<<Ee/256,256,0,stream>>>(src, dst, flag, rowptr_d, fill_d, slist,
                                      rowptr_s, fill_s, cwlist, dinv);
  gat_aggregate<<<Nn,256,0,stream>>>(hbf, lgs, lgd, rowptr_d, slist, Hfeat, Hbf);

  // ---- residual GCN layers ----
  for (int l=0;l<NLAY;l++){
    spmm_bf<<<Nn,256,0,stream>>>(Hbf, Phi, rowptr_s, cwlist, dinv);
    gemm_bf<<<dim3(HIDC/128, (Nn*HEADS)/128),256,0,stream>>>(Phi,
        WgcnT + (size_t)l*HIDC*HIDC,
        Hfeat, Hfeat, (l==NLAY-1)? nullptr : Hbf, Nn*HEADS, HIDC, HIDC, 1);
  }

  // ---- pooling + FC ----
  graph_offsets<<<1,256,0,stream>>>(batch, goff);
  pool_accum<<<dim3(Nn/32, FW/256),256,0,stream>>>(Hfeat, batch, psum);
  final_out<<<GG,256,0,stream>>>(psum, goff, fc_w, fc_b, out);
}